// Round 5
// baseline (257.091 us; speedup 1.0000x reference)
//
#include <hip/hip_runtime.h>

typedef unsigned short u16;
typedef __bf16 bf16x8 __attribute__((ext_vector_type(8)));
typedef float f32x4 __attribute__((ext_vector_type(4)));
typedef unsigned short u16x8 __attribute__((ext_vector_type(8)));
typedef unsigned short u16x4 __attribute__((ext_vector_type(4)));

__device__ __forceinline__ float bf2f(u16 u){
  union { unsigned i; float f; } v; v.i = ((unsigned)u) << 16; return v.f;
}
__device__ __forceinline__ u16 f2bf(float f){
  union { float f; unsigned i; } v; v.f = f;
  unsigned r = v.i + 0x7FFFu + ((v.i >> 16) & 1u);
  return (u16)(r >> 16);
}
// elu(x)+1:  x>0 -> x+1 ; x<=0 -> exp(x)
__device__ __forceinline__ float elup(float x){ return x > 0.f ? x + 1.f : expf(x); }

__device__ __forceinline__ void gload_lds16(const void* gsrc, void* ldst){
  __builtin_amdgcn_global_load_lds(
      (__attribute__((address_space(1))) void*)(unsigned long long)gsrc,
      (__attribute__((address_space(3))) void*)(unsigned)(unsigned long long)ldst,
      16, 0, 0);
}

// ---------------- transpose + cast: in[R][Cc] (f32) -> out[Cc][R] (bf16) ----------------
__global__ __launch_bounds__(256) void transpose_f32_bf16(const float* __restrict__ in, u16* __restrict__ out,
                                                          int R, int Cc){
  __shared__ u16 tile[32][33];
  int c0 = blockIdx.x * 32, r0 = blockIdx.y * 32;
  int tx = threadIdx.x, ty = threadIdx.y; // 32 x 8
  #pragma unroll
  for (int i=0;i<4;i++)
    tile[ty + i*8][tx] = f2bf(in[(size_t)(r0 + ty + i*8)*Cc + c0 + tx]);
  __syncthreads();
  #pragma unroll
  for (int i=0;i<4;i++)
    out[(size_t)(c0 + ty + i*8)*R + r0 + tx] = tile[tx][ty + i*8];
}

// ---------------- LayerNorm (row of 1024): f32 in, bf16 out ----------------
__global__ __launch_bounds__(256) void ln_f32(const float* __restrict__ x, const float* __restrict__ g,
                                              const float* __restrict__ b, u16* __restrict__ y){
  int row = blockIdx.x, tid = threadIdx.x;
  size_t base = (size_t)row*1024 + tid*4;
  f32x4 xv = *(const f32x4*)(x + base);
  float v0=xv[0], v1=xv[1], v2=xv[2], v3=xv[3];
  float s  = v0+v1+v2+v3;
  float s2 = v0*v0+v1*v1+v2*v2+v3*v3;
  #pragma unroll
  for (int off=32; off>0; off>>=1){ s += __shfl_xor(s, off); s2 += __shfl_xor(s2, off); }
  __shared__ float ls[4], ls2[4];
  if ((tid & 63) == 0){ ls[tid>>6] = s; ls2[tid>>6] = s2; }
  __syncthreads();
  float ts = ls[0]+ls[1]+ls[2]+ls[3];
  float ts2 = ls2[0]+ls2[1]+ls2[2]+ls2[3];
  float mean = ts*(1.f/1024.f);
  float var  = ts2*(1.f/1024.f) - mean*mean;
  float rstd = rsqrtf(var + 1e-5f);
  f32x4 gv = *(const f32x4*)(g + tid*4);
  f32x4 bv = *(const f32x4*)(b + tid*4);
  u16x4 ov;
  ov[0]=f2bf((v0-mean)*rstd*gv[0]+bv[0]);
  ov[1]=f2bf((v1-mean)*rstd*gv[1]+bv[1]);
  ov[2]=f2bf((v2-mean)*rstd*gv[2]+bv[2]);
  ov[3]=f2bf((v3-mean)*rstd*gv[3]+bv[3]);
  *(u16x4*)(y + base) = ov;
}

// ---------------- GEMM: C[M][N] = A[M][K] * BT[N][K]^T + bias, fused epilogue ----------------
// EPI 0: bf16 out.  1: gelu -> bf16 out.  2: + f32 residual -> f32 out.
template<int EPI>
__global__ __launch_bounds__(256) void gemm_bt(const u16* __restrict__ A, const u16* __restrict__ BT,
                                               const float* __restrict__ bias, const float* __restrict__ res,
                                               void* __restrict__ out, int N, int K){
  __shared__ u16 As[128*32];
  __shared__ u16 Bs[128*32];
  int tid = threadIdx.x;
  int w = tid >> 6, lane = tid & 63;
  int m0 = blockIdx.x * 128, n0 = blockIdx.y * 128;

  f32x4 acc[4][4] = {};

  const u16* aSrc = A  + (size_t)(m0 + w*32 + (lane>>2))*K + (lane&3)*8;
  const u16* bSrc = BT + (size_t)(n0 + w*32 + (lane>>2))*K + (lane&3)*8;
  u16* aD0 = As + (w*2)*512;
  u16* bD0 = Bs + (w*2)*512;
  int r0 = (w>>1)*64, c0 = (w&1)*64;
  int lrow = lane & 15, lk = (lane>>4)*8;

  for (int k0 = 0; k0 < K; k0 += 32){
    gload_lds16(aSrc + k0,                aD0);
    gload_lds16(aSrc + (size_t)16*K + k0, aD0 + 512);
    gload_lds16(bSrc + k0,                bD0);
    gload_lds16(bSrc + (size_t)16*K + k0, bD0 + 512);
    __syncthreads();
    bf16x8 af[4], bfv[4];
    #pragma unroll
    for (int mi=0;mi<4;mi++) af[mi]  = *(const bf16x8*)(As + (r0 + mi*16 + lrow)*32 + lk);
    #pragma unroll
    for (int ni=0;ni<4;ni++) bfv[ni] = *(const bf16x8*)(Bs + (c0 + ni*16 + lrow)*32 + lk);
    #pragma unroll
    for (int mi=0;mi<4;mi++)
      #pragma unroll
      for (int ni=0;ni<4;ni++)
        acc[mi][ni] = __builtin_amdgcn_mfma_f32_16x16x32_bf16(af[mi], bfv[ni], acc[mi][ni], 0, 0, 0);
    __syncthreads();
  }

  int lgr = lane >> 4;
  #pragma unroll
  for (int mi=0;mi<4;mi++){
    #pragma unroll
    for (int j=0;j<4;j++){
      int row = m0 + r0 + mi*16 + lgr*4 + j;
      #pragma unroll
      for (int ni=0;ni<4;ni++){
        int col = n0 + c0 + ni*16 + lrow;
        size_t idx = (size_t)row*N + col;
        float v = acc[mi][ni][j] + bias[col];
        if constexpr (EPI == 0){
          ((u16*)out)[idx] = f2bf(v);
        } else if constexpr (EPI == 1){
          v = 0.5f * v * (1.f + erff(v * 0.70710678118654752f));
          ((u16*)out)[idx] = f2bf(v);
        } else {
          ((float*)out)[idx] = v + res[idx];
        }
      }
    }
  }
}

// ---------------- attention: per-(head,chunk) sums of K outer v and K ----------------
__global__ __launch_bounds__(256) void attn_chunksum(const u16* __restrict__ qkv, float* __restrict__ S,
                                                     float* __restrict__ Ks){
  __shared__ float Kf[4096], Vf[4096];
  int c = blockIdx.x, h = blockIdx.y, tid = threadIdx.x;
  int t = tid >> 2, seg = tid & 3, e0 = seg*16;
  size_t rowb = (size_t)(c*64 + t)*3072 + h*64 + e0;
  u16x8 k0 = *(const u16x8*)(qkv + rowb + 1024);
  u16x8 k1 = *(const u16x8*)(qkv + rowb + 1032);
  u16x8 v0 = *(const u16x8*)(qkv + rowb + 2048);
  u16x8 v1 = *(const u16x8*)(qkv + rowb + 2056);
  #pragma unroll
  for (int i=0;i<8;i++){
    Kf[t*64 + e0 + i]     = elup(bf2f(k0[i]));
    Kf[t*64 + e0 + 8 + i] = elup(bf2f(k1[i]));
    Vf[t*64 + e0 + i]     = bf2f(v0[i]);
    Vf[t*64 + e0 + 8 + i] = bf2f(v1[i]);
  }
  __syncthreads();
  int d = t;
  f32x4 s4[4] = {};
  float ks = 0.f;
  for (int tt=0; tt<64; tt++){
    float kd = Kf[tt*64 + d];
    ks += kd;
    const f32x4* vp = (const f32x4*)&Vf[tt*64 + e0];
    s4[0] += kd*vp[0]; s4[1] += kd*vp[1]; s4[2] += kd*vp[2]; s4[3] += kd*vp[3];
  }
  size_t base = (size_t)(h*32 + c)*4096 + (size_t)d*64 + e0;
  f32x4* so = (f32x4*)(S + base);
  so[0]=s4[0]; so[1]=s4[1]; so[2]=s4[2]; so[3]=s4[3];
  if (seg == 0) Ks[(size_t)(h*32 + c)*64 + d] = ks;
}

// ---------------- attention: exclusive prefix over chunks (per head, element-parallel) ----------------
__global__ __launch_bounds__(256) void attn_prefix(float* __restrict__ S, float* __restrict__ Ks){
  int g = blockIdx.x, h = blockIdx.y, tid = threadIdx.x;
  size_t hb = (size_t)h * 32 * 4096;
  int idx = g*256 + tid;
  float run = 0.f;
  for (int c=0; c<32; c++){
    size_t p = hb + (size_t)c*4096 + idx;
    float v = S[p]; S[p] = run; run += v;
  }
  if (g == 0 && tid < 64){
    float r2 = 0.f;
    for (int c=0; c<32; c++){
      size_t p = (size_t)(h*32 + c)*64 + tid;
      float v = Ks[p]; Ks[p] = r2; r2 += v;
    }
  }
}

// ---------------- attention: O = Q*S_prev + tril(Q K^T) V, den = Q*(k_prev + cumsum K) ----------------
__global__ __launch_bounds__(256) void attn_out(const u16* __restrict__ qkv, const float* __restrict__ S,
                                                const float* __restrict__ Ks, u16* __restrict__ o){
  __shared__ float BufA[4096]; // Q, then A = masked QK^T
  __shared__ float BufB[4096]; // K, then V
  __shared__ float BufC[4096]; // S_prev
  __shared__ float kp[64];
  int c = blockIdx.x, h = blockIdx.y, tid = threadIdx.x;
  int t = tid >> 2, seg = tid & 3, e0 = seg*16;

  size_t rowb = (size_t)(c*64 + t)*3072 + h*64 + e0;
  u16x8 q0 = *(const u16x8*)(qkv + rowb);
  u16x8 q1 = *(const u16x8*)(qkv + rowb + 8);
  u16x8 k0 = *(const u16x8*)(qkv + rowb + 1024);
  u16x8 k1 = *(const u16x8*)(qkv + rowb + 1032);
  u16x8 v0 = *(const u16x8*)(qkv + rowb + 2048);
  u16x8 v1 = *(const u16x8*)(qkv + rowb + 2056);
  #pragma unroll
  for (int i=0;i<8;i++){
    BufA[t*64 + e0 + i]     = elup(bf2f(q0[i]));
    BufA[t*64 + e0 + 8 + i] = elup(bf2f(q1[i]));
    BufB[t*64 + e0 + i]     = elup(bf2f(k0[i]));
    BufB[t*64 + e0 + 8 + i] = elup(bf2f(k1[i]));
  }
  size_t sbase = (size_t)(h*32 + c)*4096;
  {
    const f32x4* sg = (const f32x4*)(S + sbase + tid*16);
    f32x4* sl = (f32x4*)&BufC[tid*16];
    sl[0]=sg[0]; sl[1]=sg[1]; sl[2]=sg[2]; sl[3]=sg[3];
  }
  if (tid < 64) kp[tid] = Ks[(size_t)(h*32 + c)*64 + tid];
  __syncthreads();

  // Q row -> registers (static indexing only)
  f32x4 qv[16];
  {
    const f32x4* qp = (const f32x4*)&BufA[t*64];
    #pragma unroll
    for (int i=0;i<16;i++) qv[i] = qp[i];
  }

  // phase 1a: num = Q * S_prev (this thread's 16 e's), den0 = Q . k_prev
  f32x4 num[4] = {};
  float den = 0.f;
  #pragma unroll
  for (int d=0; d<64; d++){
    float qd = qv[d>>2][d&3];
    den += qd * kp[d];
    const f32x4* sp = (const f32x4*)&BufC[d*64 + e0];
    num[0] += qd*sp[0]; num[1] += qd*sp[1]; num[2] += qd*sp[2]; num[3] += qd*sp[3];
  }

  // phase 1b: a[j] = Q[t] . K[s],  s = seg*16 + j, masked to s<=t
  float a[16];
  #pragma unroll
  for (int j=0;j<16;j++){
    int s = e0 + j;
    const f32x4* kr = (const f32x4*)&BufB[s*64];
    f32x4 ac = {};
    #pragma unroll
    for (int d4=0; d4<16; d4++) ac += qv[d4]*kr[d4];
    float av = ac[0]+ac[1]+ac[2]+ac[3];
    a[j] = (s <= t) ? av : 0.f;
  }
  __syncthreads();   // all Q/K LDS reads done
  #pragma unroll
  for (int j=0;j<16;j++) BufA[t*64 + e0 + j] = a[j];   // A into Q's buffer
  #pragma unroll
  for (int i=0;i<8;i++){                                // V into K's buffer
    BufB[t*64 + e0 + i]     = bf2f(v0[i]);
    BufB[t*64 + e0 + 8 + i] = bf2f(v1[i]);
  }
  __syncthreads();

  // phase 2: num += A[t][s] * V[s][e], den += sum_s A[t][s]
  #pragma unroll 4
  for (int s=0; s<64; s++){
    float av = BufA[t*64 + s];
    den += av;
    const f32x4* vp = (const f32x4*)&BufB[s*64 + e0];
    num[0] += av*vp[0]; num[1] += av*vp[1]; num[2] += av*vp[2]; num[3] += av*vp[3];
  }

  float inv = 1.f/(den + 1e-6f);
  u16x8 w0, w1;
  #pragma unroll
  for (int i=0;i<8;i++){
    w0[i] = f2bf(num[i>>2][i&3]*inv);
    w1[i] = f2bf(num[2 + (i>>2)][i&3]*inv);
  }
  size_t ob = (size_t)(c*64 + t)*1024 + h*64 + e0;
  *(u16x8*)(o + ob)     = w0;
  *(u16x8*)(o + ob + 8) = w1;
}

// ---------------- launch ----------------
extern "C" void kernel_launch(void* const* d_in, const int* in_sizes, int n_in,
                              void* d_out, int out_size, void* d_ws, size_t ws_size,
                              hipStream_t stream) {
  (void)in_sizes; (void)n_in; (void)out_size; (void)ws_size;
  const float* x     = (const float*)d_in[0];
  const float* qkv_w = (const float*)d_in[1];
  const float* qkv_b = (const float*)d_in[2];
  const float* out_w = (const float*)d_in[3];
  const float* out_b = (const float*)d_in[4];
  const float* ln1_g = (const float*)d_in[5];
  const float* ln1_b = (const float*)d_in[6];
  const float* ln2_g = (const float*)d_in[7];
  const float* ln2_b = (const float*)d_in[8];
  const float* w1    = (const float*)d_in[9];
  const float* b1    = (const float*)d_in[10];
  const float* w2    = (const float*)d_in[11];
  const float* b2    = (const float*)d_in[12];

  char* ws = (char*)d_ws;
  u16*   wT_qkv = (u16*)  (ws);              // 3072 x 1024 bf16
  u16*   wT_out = (u16*)  (ws +  6291456);   // 1024 x 1024 bf16
  u16*   wT_w1  = (u16*)  (ws +  8388608);   // 4096 x 1024 bf16
  u16*   wT_w2  = (u16*)  (ws + 16777216);   // 1024 x 4096 bf16
  u16*   h1     = (u16*)  (ws + 25165824);   // 2048 x 1024 bf16 (reused as o)
  u16*   qkv    = (u16*)  (ws + 29360128);   // 2048 x 3072 bf16 (reused as a1, spills into dead Ssum)
  float* Ssum   = (float*)(ws + 41943040);   // 16*32*4096 f32
  float* ksum   = (float*)(ws + 50331648);   // 16*32*64 f32
  float* x2     = (float*)(ws + 50462720);   // 2048 x 1024 f32
  u16*   h2     = (u16*)  (ws + 58851328);   // 2048 x 1024 bf16
  u16*   o      = h1;
  u16*   a1     = qkv;                        // 2048 x 4096 bf16
  float* outp   = (float*)d_out;

  dim3 tb(32, 8);
  transpose_f32_bf16<<<dim3(3072/32, 1024/32), tb, 0, stream>>>(qkv_w, wT_qkv, 1024, 3072);
  transpose_f32_bf16<<<dim3(1024/32, 1024/32), tb, 0, stream>>>(out_w, wT_out, 1024, 1024);
  transpose_f32_bf16<<<dim3(4096/32, 1024/32), tb, 0, stream>>>(w1,    wT_w1,  1024, 4096);
  transpose_f32_bf16<<<dim3(1024/32, 4096/32), tb, 0, stream>>>(w2,    wT_w2,  4096, 1024);

  ln_f32<<<2048, 256, 0, stream>>>(x, ln1_g, ln1_b, h1);
  gemm_bt<0><<<dim3(16, 24), 256, 0, stream>>>(h1, wT_qkv, qkv_b, nullptr, qkv, 3072, 1024);

  attn_chunksum<<<dim3(32, 16), 256, 0, stream>>>(qkv, Ssum, ksum);
  attn_prefix  <<<dim3(16, 16), 256, 0, stream>>>(Ssum, ksum);
  attn_out     <<<dim3(32, 16), 256, 0, stream>>>(qkv, Ssum, ksum, o);

  gemm_bt<2><<<dim3(16, 8),  256, 0, stream>>>(o, wT_out, out_b, x, (void*)x2, 1024, 1024);
  ln_f32<<<2048, 256, 0, stream>>>(x2, ln2_g, ln2_b, h2);
  gemm_bt<1><<<dim3(16, 32), 256, 0, stream>>>(h2, wT_w1, b1, nullptr, a1, 4096, 1024);
  gemm_bt<2><<<dim3(16, 8),  256, 0, stream>>>(a1, wT_w2, b2, x2, (void*)outp, 1024, 4096);
}

// Round 6
// 201.274 us; speedup vs baseline: 1.2773x; 1.2773x over previous
//
#include <hip/hip_runtime.h>

typedef unsigned short u16;
typedef __bf16 bf16x8 __attribute__((ext_vector_type(8)));
typedef float f32x4 __attribute__((ext_vector_type(4)));
typedef unsigned short u16x8 __attribute__((ext_vector_type(8)));
typedef unsigned short u16x4 __attribute__((ext_vector_type(4)));

__device__ __forceinline__ float bf2f(u16 u){
  union { unsigned i; float f; } v; v.i = ((unsigned)u) << 16; return v.f;
}
__device__ __forceinline__ u16 f2bf(float f){
  union { float f; unsigned i; } v; v.f = f;
  unsigned r = v.i + 0x7FFFu + ((v.i >> 16) & 1u);
  return (u16)(r >> 16);
}
// elu(x)+1:  x>0 -> x+1 ; x<=0 -> exp(x)
__device__ __forceinline__ float elup(float x){ return x > 0.f ? x + 1.f : expf(x); }

__device__ __forceinline__ void gload_lds16(const void* gsrc, void* ldst){
  __builtin_amdgcn_global_load_lds(
      (__attribute__((address_space(1))) void*)(unsigned long long)gsrc,
      (__attribute__((address_space(3))) void*)(unsigned)(unsigned long long)ldst,
      16, 0, 0);
}

// ---------------- fused transpose+cast: 4 matrices, in[R][Cc] f32 -> out[Cc][R] bf16 ----------------
struct TD { const float* in; u16* out; int R, Cc, cx, ntiles; };

__global__ __launch_bounds__(256) void transpose4(TD d0, TD d1, TD d2, TD d3){
  __shared__ u16 tile[32][33];
  int b = blockIdx.x;
  TD d;
  if (b < d0.ntiles) d = d0;
  else { b -= d0.ntiles;
    if (b < d1.ntiles) d = d1;
    else { b -= d1.ntiles;
      if (b < d2.ntiles) d = d2;
      else { b -= d2.ntiles; d = d3; } } }
  int c0 = (b % d.cx) * 32, r0 = (b / d.cx) * 32;
  int tx = threadIdx.x, ty = threadIdx.y; // 32 x 8
  #pragma unroll
  for (int i=0;i<4;i++)
    tile[ty + i*8][tx] = f2bf(d.in[(size_t)(r0 + ty + i*8)*d.Cc + c0 + tx]);
  __syncthreads();
  #pragma unroll
  for (int i=0;i<4;i++)
    d.out[(size_t)(c0 + ty + i*8)*d.R + r0 + tx] = tile[tx][ty + i*8];
}

// ---------------- LayerNorm (row of 1024): f32 in, bf16 out ----------------
__global__ __launch_bounds__(256) void ln_f32(const float* __restrict__ x, const float* __restrict__ g,
                                              const float* __restrict__ b, u16* __restrict__ y){
  int row = blockIdx.x, tid = threadIdx.x;
  size_t base = (size_t)row*1024 + tid*4;
  f32x4 xv = *(const f32x4*)(x + base);
  float v0=xv[0], v1=xv[1], v2=xv[2], v3=xv[3];
  float s  = v0+v1+v2+v3;
  float s2 = v0*v0+v1*v1+v2*v2+v3*v3;
  #pragma unroll
  for (int off=32; off>0; off>>=1){ s += __shfl_xor(s, off); s2 += __shfl_xor(s2, off); }
  __shared__ float ls[4], ls2[4];
  if ((tid & 63) == 0){ ls[tid>>6] = s; ls2[tid>>6] = s2; }
  __syncthreads();
  float ts = ls[0]+ls[1]+ls[2]+ls[3];
  float ts2 = ls2[0]+ls2[1]+ls2[2]+ls2[3];
  float mean = ts*(1.f/1024.f);
  float var  = ts2*(1.f/1024.f) - mean*mean;
  float rstd = rsqrtf(var + 1e-5f);
  f32x4 gv = *(const f32x4*)(g + tid*4);
  f32x4 bv = *(const f32x4*)(b + tid*4);
  u16x4 ov;
  ov[0]=f2bf((v0-mean)*rstd*gv[0]+bv[0]);
  ov[1]=f2bf((v1-mean)*rstd*gv[1]+bv[1]);
  ov[2]=f2bf((v2-mean)*rstd*gv[2]+bv[2]);
  ov[3]=f2bf((v3-mean)*rstd*gv[3]+bv[3]);
  *(u16x4*)(y + base) = ov;
}

// ---------------- GEMM: C[M][N] = A[M][K] * BT[N][K]^T (+ bias), fused epilogue ----------------
// EPI 0: +bias -> bf16 out.   1: gelu(+bias) -> bf16 out.   2: +bias +f32 residual -> f32 out.
// EPI 3: split-K bf16 PARTIAL out (no bias); gridDim.z = #splits, partial z at out + z*pstride.
template<int EPI>
__global__ __launch_bounds__(256) void gemm_bt(const u16* __restrict__ A, const u16* __restrict__ BT,
                                               const float* __restrict__ bias, const float* __restrict__ res,
                                               void* __restrict__ out, int N, int K, size_t pstride){
  __shared__ u16 As[128*32];
  __shared__ u16 Bs[128*32];
  int tid = threadIdx.x;
  int w = tid >> 6, lane = tid & 63;
  int m0 = blockIdx.x * 128, n0 = blockIdx.y * 128;
  int Kc = K / gridDim.z;
  int kbase = blockIdx.z * Kc;

  f32x4 acc[4][4] = {};

  const u16* aSrc = A  + (size_t)(m0 + w*32 + (lane>>2))*K + kbase + (lane&3)*8;
  const u16* bSrc = BT + (size_t)(n0 + w*32 + (lane>>2))*K + kbase + (lane&3)*8;
  u16* aD0 = As + (w*2)*512;
  u16* bD0 = Bs + (w*2)*512;
  int r0 = (w>>1)*64, c0 = (w&1)*64;
  int lrow = lane & 15, lk = (lane>>4)*8;

  for (int k0 = 0; k0 < Kc; k0 += 32){
    gload_lds16(aSrc + k0,                aD0);
    gload_lds16(aSrc + (size_t)16*K + k0, aD0 + 512);
    gload_lds16(bSrc + k0,                bD0);
    gload_lds16(bSrc + (size_t)16*K + k0, bD0 + 512);
    __syncthreads();
    bf16x8 af[4], bfv[4];
    #pragma unroll
    for (int mi=0;mi<4;mi++) af[mi]  = *(const bf16x8*)(As + (r0 + mi*16 + lrow)*32 + lk);
    #pragma unroll
    for (int ni=0;ni<4;ni++) bfv[ni] = *(const bf16x8*)(Bs + (c0 + ni*16 + lrow)*32 + lk);
    #pragma unroll
    for (int mi=0;mi<4;mi++)
      #pragma unroll
      for (int ni=0;ni<4;ni++)
        acc[mi][ni] = __builtin_amdgcn_mfma_f32_16x16x32_bf16(af[mi], bfv[ni], acc[mi][ni], 0, 0, 0);
    __syncthreads();
  }

  int lgr = lane >> 4;
  u16* pout = (EPI == 3) ? ((u16*)out + (size_t)blockIdx.z * pstride) : (u16*)out;
  #pragma unroll
  for (int mi=0;mi<4;mi++){
    #pragma unroll
    for (int j=0;j<4;j++){
      int row = m0 + r0 + mi*16 + lgr*4 + j;
      #pragma unroll
      for (int ni=0;ni<4;ni++){
        int col = n0 + c0 + ni*16 + lrow;
        size_t idx = (size_t)row*N + col;
        if constexpr (EPI == 3){
          pout[idx] = f2bf(acc[mi][ni][j]);
        } else {
          float v = acc[mi][ni][j] + bias[col];
          if constexpr (EPI == 0){
            ((u16*)out)[idx] = f2bf(v);
          } else if constexpr (EPI == 1){
            v = 0.5f * v * (1.f + erff(v * 0.70710678118654752f));
            ((u16*)out)[idx] = f2bf(v);
          } else {
            ((float*)out)[idx] = v + res[idx];
          }
        }
      }
    }
  }
}

// ---------------- split-K reduction: out = sum(partials) + bias + res  (M=2048, N=1024) ----------------
__global__ __launch_bounds__(256) void reduce2(const u16* __restrict__ P0, const u16* __restrict__ P1,
                                               const float* __restrict__ bias, const float* __restrict__ res,
                                               float* __restrict__ out){
  size_t i = ((size_t)blockIdx.x*256 + threadIdx.x)*4;
  u16x4 a = *(const u16x4*)(P0 + i);
  u16x4 b = *(const u16x4*)(P1 + i);
  f32x4 rv = *(const f32x4*)(res + i);
  f32x4 bv = *(const f32x4*)(bias + (i & 1023));
  f32x4 o;
  #pragma unroll
  for (int j=0;j<4;j++) o[j] = bf2f(a[j]) + bf2f(b[j]) + bv[j] + rv[j];
  *(f32x4*)(out + i) = o;
}

__global__ __launch_bounds__(256) void reduce4(const u16* __restrict__ P0, const u16* __restrict__ P1,
                                               const u16* __restrict__ P2, const u16* __restrict__ P3,
                                               const float* __restrict__ bias, const float* __restrict__ res,
                                               float* __restrict__ out){
  size_t i = ((size_t)blockIdx.x*256 + threadIdx.x)*4;
  u16x4 a = *(const u16x4*)(P0 + i);
  u16x4 b = *(const u16x4*)(P1 + i);
  u16x4 c = *(const u16x4*)(P2 + i);
  u16x4 d = *(const u16x4*)(P3 + i);
  f32x4 rv = *(const f32x4*)(res + i);
  f32x4 bv = *(const f32x4*)(bias + (i & 1023));
  f32x4 o;
  #pragma unroll
  for (int j=0;j<4;j++) o[j] = (bf2f(a[j]) + bf2f(b[j])) + (bf2f(c[j]) + bf2f(d[j])) + bv[j] + rv[j];
  *(f32x4*)(out + i) = o;
}

// ---------------- attention: per-(head,chunk) sums of K outer v and K ----------------
__global__ __launch_bounds__(256) void attn_chunksum(const u16* __restrict__ qkv, float* __restrict__ S,
                                                     float* __restrict__ Ks){
  __shared__ float Kf[4096], Vf[4096];
  int c = blockIdx.x, h = blockIdx.y, tid = threadIdx.x;
  int t = tid >> 2, seg = tid & 3, e0 = seg*16;
  size_t rowb = (size_t)(c*64 + t)*3072 + h*64 + e0;
  u16x8 k0 = *(const u16x8*)(qkv + rowb + 1024);
  u16x8 k1 = *(const u16x8*)(qkv + rowb + 1032);
  u16x8 v0 = *(const u16x8*)(qkv + rowb + 2048);
  u16x8 v1 = *(const u16x8*)(qkv + rowb + 2056);
  #pragma unroll
  for (int i=0;i<8;i++){
    Kf[t*64 + e0 + i]     = elup(bf2f(k0[i]));
    Kf[t*64 + e0 + 8 + i] = elup(bf2f(k1[i]));
    Vf[t*64 + e0 + i]     = bf2f(v0[i]);
    Vf[t*64 + e0 + 8 + i] = bf2f(v1[i]);
  }
  __syncthreads();
  int d = t;
  f32x4 s4[4] = {};
  float ks = 0.f;
  for (int tt=0; tt<64; tt++){
    float kd = Kf[tt*64 + d];
    ks += kd;
    const f32x4* vp = (const f32x4*)&Vf[tt*64 + e0];
    s4[0] += kd*vp[0]; s4[1] += kd*vp[1]; s4[2] += kd*vp[2]; s4[3] += kd*vp[3];
  }
  size_t base = (size_t)(h*32 + c)*4096 + (size_t)d*64 + e0;
  f32x4* so = (f32x4*)(S + base);
  so[0]=s4[0]; so[1]=s4[1]; so[2]=s4[2]; so[3]=s4[3];
  if (seg == 0) Ks[(size_t)(h*32 + c)*64 + d] = ks;
}

// ---------------- attention: exclusive prefix over chunks (per head, element-parallel) ----------------
__global__ __launch_bounds__(256) void attn_prefix(float* __restrict__ S, float* __restrict__ Ks){
  int g = blockIdx.x, h = blockIdx.y, tid = threadIdx.x;
  size_t hb = (size_t)h * 32 * 4096;
  int idx = g*256 + tid;
  float run = 0.f;
  for (int c=0; c<32; c++){
    size_t p = hb + (size_t)c*4096 + idx;
    float v = S[p]; S[p] = run; run += v;
  }
  if (g == 0 && tid < 64){
    float r2 = 0.f;
    for (int c=0; c<32; c++){
      size_t p = (size_t)(h*32 + c)*64 + tid;
      float v = Ks[p]; Ks[p] = r2; r2 += v;
    }
  }
}

// ---------------- attention: O = Q*S_prev + tril(Q K^T) V, den = Q*(k_prev + cumsum K) ----------------
__global__ __launch_bounds__(256) void attn_out(const u16* __restrict__ qkv, const float* __restrict__ S,
                                                const float* __restrict__ Ks, u16* __restrict__ o){
  __shared__ float BufA[4096]; // Q, then A = masked QK^T
  __shared__ float BufB[4096]; // K, then V
  __shared__ float BufC[4096]; // S_prev
  __shared__ float kp[64];
  int c = blockIdx.x, h = blockIdx.y, tid = threadIdx.x;
  int t = tid >> 2, seg = tid & 3, e0 = seg*16;

  size_t rowb = (size_t)(c*64 + t)*3072 + h*64 + e0;
  u16x8 q0 = *(const u16x8*)(qkv + rowb);
  u16x8 q1 = *(const u16x8*)(qkv + rowb + 8);
  u16x8 k0 = *(const u16x8*)(qkv + rowb + 1024);
  u16x8 k1 = *(const u16x8*)(qkv + rowb + 1032);
  u16x8 v0 = *(const u16x8*)(qkv + rowb + 2048);
  u16x8 v1 = *(const u16x8*)(qkv + rowb + 2056);
  #pragma unroll
  for (int i=0;i<8;i++){
    BufA[t*64 + e0 + i]     = elup(bf2f(q0[i]));
    BufA[t*64 + e0 + 8 + i] = elup(bf2f(q1[i]));
    BufB[t*64 + e0 + i]     = elup(bf2f(k0[i]));
    BufB[t*64 + e0 + 8 + i] = elup(bf2f(k1[i]));
  }
  size_t sbase = (size_t)(h*32 + c)*4096;
  {
    const f32x4* sg = (const f32x4*)(S + sbase + tid*16);
    f32x4* sl = (f32x4*)&BufC[tid*16];
    sl[0]=sg[0]; sl[1]=sg[1]; sl[2]=sg[2]; sl[3]=sg[3];
  }
  if (tid < 64) kp[tid] = Ks[(size_t)(h*32 + c)*64 + tid];
  __syncthreads();

  // Q row -> registers (static indexing only)
  f32x4 qv[16];
  {
    const f32x4* qp = (const f32x4*)&BufA[t*64];
    #pragma unroll
    for (int i=0;i<16;i++) qv[i] = qp[i];
  }

  // phase 1a: num = Q * S_prev (this thread's 16 e's), den0 = Q . k_prev
  f32x4 num[4] = {};
  float den = 0.f;
  #pragma unroll
  for (int d=0; d<64; d++){
    float qd = qv[d>>2][d&3];
    den += qd * kp[d];
    const f32x4* sp = (const f32x4*)&BufC[d*64 + e0];
    num[0] += qd*sp[0]; num[1] += qd*sp[1]; num[2] += qd*sp[2]; num[3] += qd*sp[3];
  }

  // phase 1b: a[j] = Q[t] . K[s],  s = seg*16 + j, masked to s<=t
  float a[16];
  #pragma unroll
  for (int j=0;j<16;j++){
    int s = e0 + j;
    const f32x4* kr = (const f32x4*)&BufB[s*64];
    f32x4 ac = {};
    #pragma unroll
    for (int d4=0; d4<16; d4++) ac += qv[d4]*kr[d4];
    float av = ac[0]+ac[1]+ac[2]+ac[3];
    a[j] = (s <= t) ? av : 0.f;
  }
  __syncthreads();   // all Q/K LDS reads done
  #pragma unroll
  for (int j=0;j<16;j++) BufA[t*64 + e0 + j] = a[j];   // A into Q's buffer
  #pragma unroll
  for (int i=0;i<8;i++){                                // V into K's buffer
    BufB[t*64 + e0 + i]     = bf2f(v0[i]);
    BufB[t*64 + e0 + 8 + i] = bf2f(v1[i]);
  }
  __syncthreads();

  // phase 2: num += A[t][s] * V[s][e], den += sum_s A[t][s]
  #pragma unroll 4
  for (int s=0; s<64; s++){
    float av = BufA[t*64 + s];
    den += av;
    const f32x4* vp = (const f32x4*)&BufB[s*64 + e0];
    num[0] += av*vp[0]; num[1] += av*vp[1]; num[2] += av*vp[2]; num[3] += av*vp[3];
  }

  float inv = 1.f/(den + 1e-6f);
  u16x8 w0, w1;
  #pragma unroll
  for (int i=0;i<8;i++){
    w0[i] = f2bf(num[i>>2][i&3]*inv);
    w1[i] = f2bf(num[2 + (i>>2)][i&3]*inv);
  }
  size_t ob = (size_t)(c*64 + t)*1024 + h*64 + e0;
  *(u16x8*)(o + ob)     = w0;
  *(u16x8*)(o + ob + 8) = w1;
}

// ---------------- launch ----------------
extern "C" void kernel_launch(void* const* d_in, const int* in_sizes, int n_in,
                              void* d_out, int out_size, void* d_ws, size_t ws_size,
                              hipStream_t stream) {
  (void)in_sizes; (void)n_in; (void)out_size; (void)ws_size;
  const float* x     = (const float*)d_in[0];
  const float* qkv_w = (const float*)d_in[1];
  const float* qkv_b = (const float*)d_in[2];
  const float* out_w = (const float*)d_in[3];
  const float* out_b = (const float*)d_in[4];
  const float* ln1_g = (const float*)d_in[5];
  const float* ln1_b = (const float*)d_in[6];
  const float* ln2_g = (const float*)d_in[7];
  const float* ln2_b = (const float*)d_in[8];
  const float* w1    = (const float*)d_in[9];
  const float* b1    = (const float*)d_in[10];
  const float* w2    = (const float*)d_in[11];
  const float* b2    = (const float*)d_in[12];

  char* ws = (char*)d_ws;
  // lifetimes: wT_qkv dead after qkv GEMM; wT_out dead after out-proj; wT_w1 dead after MLP1;
  //            qkv dead after attn_out; Ssum dead after attn_out; h1/o dead after out-proj;
  //            h2 dead after MLP1. Partial buffers reuse exactly those dead regions.
  u16*   wT_qkv = (u16*)  (ws);              // [0, 6291456)        3072x1024 bf16
  u16*   wT_out = (u16*)  (ws +  6291456);   // [6291456, 8388608)  1024x1024 bf16
  u16*   wT_w1  = (u16*)  (ws +  8388608);   // [8388608, 16777216) 4096x1024 bf16
  u16*   wT_w2  = (u16*)  (ws + 16777216);   // [16777216, 25165824) 1024x4096 bf16
  u16*   h1     = (u16*)  (ws + 25165824);   // [25165824, 29360128) 2048x1024 bf16 (reused as o)
  u16*   qkv    = (u16*)  (ws + 29360128);   // [29360128, 41943040) 2048x3072 bf16 (a1 spills into Ssum)
  float* Ssum   = (float*)(ws + 41943040);   // [41943040, 50331648) 16*32*4096 f32
  float* ksum   = (float*)(ws + 50331648);   // 16*32*64 f32
  float* x2     = (float*)(ws + 50462720);   // [50462720, 58851328) 2048x1024 f32
  u16*   h2     = (u16*)  (ws + 58851328);   // [58851328, 63045632) 2048x1024 bf16
  u16*   o      = h1;
  u16*   a1     = qkv;                        // 2048x4096 bf16
  // out-proj split-2 partials (2048x1024 bf16 each): over dead wT_qkv and dead qkv
  u16*   Pa0    = (u16*)(ws);                         // [0, 4194304)
  u16*   Pa1    = (u16*)(ws + 29360128);              // [29360128, 33554432) — dead qkv; a1 written later
  size_t PaStride = (size_t)(29360128) / 2;           // elements (u16): Pa1 = Pa0 + stride
  // MLP2 split-4 partials: over dead wT_qkv+wT_out+wT_w1 = [0, 16777216)
  u16*   Pm0    = (u16*)(ws);
  u16*   Pm1    = (u16*)(ws +  4194304);
  u16*   Pm2    = (u16*)(ws +  8388608);
  u16*   Pm3    = (u16*)(ws + 12582912);
  size_t PmStride = 2097152;                          // elements
  float* outp   = (float*)d_out;

  TD t0{qkv_w, wT_qkv, 1024, 3072,  96, 3072};
  TD t1{out_w, wT_out, 1024, 1024,  32, 1024};
  TD t2{w1,    wT_w1,  1024, 4096, 128, 4096};
  TD t3{w2,    wT_w2,  4096, 1024,  32, 4096};
  transpose4<<<12288, dim3(32,8), 0, stream>>>(t0, t1, t2, t3);

  ln_f32<<<2048, 256, 0, stream>>>(x, ln1_g, ln1_b, h1);
  gemm_bt<0><<<dim3(16, 24, 1), 256, 0, stream>>>(h1, wT_qkv, qkv_b, nullptr, qkv, 3072, 1024, 0);

  attn_chunksum<<<dim3(32, 16), 256, 0, stream>>>(qkv, Ssum, ksum);
  attn_prefix  <<<dim3(16, 16), 256, 0, stream>>>(Ssum, ksum);
  attn_out     <<<dim3(32, 16), 256, 0, stream>>>(qkv, Ssum, ksum, o);

  // out-proj: split-K x2 -> partials -> reduce(+out_b +x) -> x2 (f32)
  gemm_bt<3><<<dim3(16, 8, 2), 256, 0, stream>>>(o, wT_out, nullptr, nullptr, Pa0, 1024, 1024, PaStride);
  reduce2<<<2048, 256, 0, stream>>>(Pa0, Pa1, out_b, x, x2);

  ln_f32<<<2048, 256, 0, stream>>>(x2, ln2_g, ln2_b, h2);
  gemm_bt<1><<<dim3(16, 32, 1), 256, 0, stream>>>(h2, wT_w1, b1, nullptr, a1, 4096, 1024, 0);

  // MLP2: split-K x4 -> partials -> reduce(+b2 +x2) -> d_out (f32)
  gemm_bt<3><<<dim3(16, 8, 4), 256, 0, stream>>>(a1, wT_w2, nullptr, nullptr, Pm0, 1024, 4096, PmStride);
  reduce4<<<2048, 256, 0, stream>>>(Pm0, Pm1, Pm2, Pm3, b2, x2, outp);
}

// Round 7
// 178.862 us; speedup vs baseline: 1.4374x; 1.1253x over previous
//
#include <hip/hip_runtime.h>

typedef unsigned short u16;
typedef __bf16 bf16x8 __attribute__((ext_vector_type(8)));
typedef float f32x4 __attribute__((ext_vector_type(4)));
typedef unsigned short u16x8 __attribute__((ext_vector_type(8)));
typedef unsigned short u16x4 __attribute__((ext_vector_type(4)));

__device__ __forceinline__ float bf2f(u16 u){
  union { unsigned i; float f; } v; v.i = ((unsigned)u) << 16; return v.f;
}
__device__ __forceinline__ u16 f2bf(float f){
  union { float f; unsigned i; } v; v.f = f;
  unsigned r = v.i + 0x7FFFu + ((v.i >> 16) & 1u);
  return (u16)(r >> 16);
}
// elu(x)+1:  x>0 -> x+1 ; x<=0 -> exp(x)
__device__ __forceinline__ float elup(float x){ return x > 0.f ? x + 1.f : expf(x); }

__device__ __forceinline__ void gload_lds16(const void* gsrc, void* ldst){
  __builtin_amdgcn_global_load_lds(
      (__attribute__((address_space(1))) void*)(unsigned long long)gsrc,
      (__attribute__((address_space(3))) void*)(unsigned)(unsigned long long)ldst,
      16, 0, 0);
}

// ---------------- fused transpose+cast: 4 matrices, in[R][Cc] f32 -> out[Cc][R] bf16 ----------------
struct TD { const float* in; u16* out; int R, Cc, cx, ntiles; };

__global__ __launch_bounds__(256) void transpose4(TD d0, TD d1, TD d2, TD d3){
  __shared__ u16 tile[32][33];
  int b = blockIdx.x;
  TD d;
  if (b < d0.ntiles) d = d0;
  else { b -= d0.ntiles;
    if (b < d1.ntiles) d = d1;
    else { b -= d1.ntiles;
      if (b < d2.ntiles) d = d2;
      else { b -= d2.ntiles; d = d3; } } }
  int c0 = (b % d.cx) * 32, r0 = (b / d.cx) * 32;
  int tx = threadIdx.x, ty = threadIdx.y; // 32 x 8
  #pragma unroll
  for (int i=0;i<4;i++)
    tile[ty + i*8][tx] = f2bf(d.in[(size_t)(r0 + ty + i*8)*d.Cc + c0 + tx]);
  __syncthreads();
  #pragma unroll
  for (int i=0;i<4;i++)
    d.out[(size_t)(c0 + ty + i*8)*d.R + r0 + tx] = tile[tx][ty + i*8];
}

// ---------------- LayerNorm (row of 1024): f32 in, bf16 out ----------------
__global__ __launch_bounds__(256) void ln_f32(const float* __restrict__ x, const float* __restrict__ g,
                                              const float* __restrict__ b, u16* __restrict__ y){
  int row = blockIdx.x, tid = threadIdx.x;
  size_t base = (size_t)row*1024 + tid*4;
  f32x4 xv = *(const f32x4*)(x + base);
  float v0=xv[0], v1=xv[1], v2=xv[2], v3=xv[3];
  float s  = v0+v1+v2+v3;
  float s2 = v0*v0+v1*v1+v2*v2+v3*v3;
  #pragma unroll
  for (int off=32; off>0; off>>=1){ s += __shfl_xor(s, off); s2 += __shfl_xor(s2, off); }
  __shared__ float ls[4], ls2[4];
  if ((tid & 63) == 0){ ls[tid>>6] = s; ls2[tid>>6] = s2; }
  __syncthreads();
  float ts = ls[0]+ls[1]+ls[2]+ls[3];
  float ts2 = ls2[0]+ls2[1]+ls2[2]+ls2[3];
  float mean = ts*(1.f/1024.f);
  float var  = ts2*(1.f/1024.f) - mean*mean;
  float rstd = rsqrtf(var + 1e-5f);
  f32x4 gv = *(const f32x4*)(g + tid*4);
  f32x4 bv = *(const f32x4*)(b + tid*4);
  u16x4 ov;
  ov[0]=f2bf((v0-mean)*rstd*gv[0]+bv[0]);
  ov[1]=f2bf((v1-mean)*rstd*gv[1]+bv[1]);
  ov[2]=f2bf((v2-mean)*rstd*gv[2]+bv[2]);
  ov[3]=f2bf((v3-mean)*rstd*gv[3]+bv[3]);
  *(u16x4*)(y + base) = ov;
}

// ---------------- GEMM: C[M][N] = A[M][K] * BT[N][K]^T (+ bias), fused epilogue ----------------
// Double-buffered LDS: stage tile t+1 before computing tile t; the single
// __syncthreads() per K-step (implicit vmcnt(0) drain) lands after compute,
// so the global_load_lds latency hides under ds_read+MFMA.
// EPI 0: +bias -> bf16 out.   1: gelu(+bias) -> bf16 out.   2: +bias +f32 residual -> f32 out.
// EPI 3: split-K bf16 PARTIAL out (no bias); gridDim.z = #splits, partial z at out + z*pstride.
template<int EPI>
__global__ __launch_bounds__(256) void gemm_bt(const u16* __restrict__ A, const u16* __restrict__ BT,
                                               const float* __restrict__ bias, const float* __restrict__ res,
                                               void* __restrict__ out, int N, int K, size_t pstride){
  __shared__ u16 As[2][128*32];
  __shared__ u16 Bs[2][128*32];
  int tid = threadIdx.x;
  int w = tid >> 6, lane = tid & 63;
  int m0 = blockIdx.x * 128, n0 = blockIdx.y * 128;
  int Kc = K / gridDim.z;
  int kbase = blockIdx.z * Kc;
  int nt = Kc / 32;

  f32x4 acc[4][4] = {};

  const u16* aSrc = A  + (size_t)(m0 + w*32 + (lane>>2))*K + kbase + (lane&3)*8;
  const u16* bSrc = BT + (size_t)(n0 + w*32 + (lane>>2))*K + kbase + (lane&3)*8;
  int r0 = (w>>1)*64, c0 = (w&1)*64;
  int lrow = lane & 15, lk = (lane>>4)*8;

  // prologue: stage tile 0 into buffer 0
  {
    u16* aD = As[0] + w*1024;
    u16* bD = Bs[0] + w*1024;
    gload_lds16(aSrc,                aD);
    gload_lds16(aSrc + (size_t)16*K, aD + 512);
    gload_lds16(bSrc,                bD);
    gload_lds16(bSrc + (size_t)16*K, bD + 512);
  }
  __syncthreads();

  int cur = 0;
  for (int t = 0; t < nt; ++t){
    // issue next tile's staging loads before computing current tile
    if (t + 1 < nt){
      int k0 = (t+1)*32;
      u16* aD = As[cur^1] + w*1024;
      u16* bD = Bs[cur^1] + w*1024;
      gload_lds16(aSrc + k0,                aD);
      gload_lds16(aSrc + (size_t)16*K + k0, aD + 512);
      gload_lds16(bSrc + k0,                bD);
      gload_lds16(bSrc + (size_t)16*K + k0, bD + 512);
    }
    const u16* Ab = As[cur];
    const u16* Bb = Bs[cur];
    bf16x8 af[4], bfv[4];
    #pragma unroll
    for (int mi=0;mi<4;mi++) af[mi]  = *(const bf16x8*)(Ab + (r0 + mi*16 + lrow)*32 + lk);
    #pragma unroll
    for (int ni=0;ni<4;ni++) bfv[ni] = *(const bf16x8*)(Bb + (c0 + ni*16 + lrow)*32 + lk);
    #pragma unroll
    for (int mi=0;mi<4;mi++)
      #pragma unroll
      for (int ni=0;ni<4;ni++)
        acc[mi][ni] = __builtin_amdgcn_mfma_f32_16x16x32_bf16(af[mi], bfv[ni], acc[mi][ni], 0, 0, 0);
    __syncthreads();   // implicit vmcnt(0): next tile fully landed; cur free to overwrite
    cur ^= 1;
  }

  int lgr = lane >> 4;
  u16* pout = (EPI == 3) ? ((u16*)out + (size_t)blockIdx.z * pstride) : (u16*)out;
  #pragma unroll
  for (int mi=0;mi<4;mi++){
    #pragma unroll
    for (int j=0;j<4;j++){
      int row = m0 + r0 + mi*16 + lgr*4 + j;
      #pragma unroll
      for (int ni=0;ni<4;ni++){
        int col = n0 + c0 + ni*16 + lrow;
        size_t idx = (size_t)row*N + col;
        if constexpr (EPI == 3){
          pout[idx] = f2bf(acc[mi][ni][j]);
        } else {
          float v = acc[mi][ni][j] + bias[col];
          if constexpr (EPI == 0){
            ((u16*)out)[idx] = f2bf(v);
          } else if constexpr (EPI == 1){
            v = 0.5f * v * (1.f + erff(v * 0.70710678118654752f));
            ((u16*)out)[idx] = f2bf(v);
          } else {
            ((float*)out)[idx] = v + res[idx];
          }
        }
      }
    }
  }
}

// ---------------- split-K reduction: out = sum(partials) + bias + res  (M=2048, N=1024) ----------------
__global__ __launch_bounds__(256) void reduce2(const u16* __restrict__ P0, const u16* __restrict__ P1,
                                               const float* __restrict__ bias, const float* __restrict__ res,
                                               float* __restrict__ out){
  size_t i = ((size_t)blockIdx.x*256 + threadIdx.x)*4;
  u16x4 a = *(const u16x4*)(P0 + i);
  u16x4 b = *(const u16x4*)(P1 + i);
  f32x4 rv = *(const f32x4*)(res + i);
  f32x4 bv = *(const f32x4*)(bias + (i & 1023));
  f32x4 o;
  #pragma unroll
  for (int j=0;j<4;j++) o[j] = bf2f(a[j]) + bf2f(b[j]) + bv[j] + rv[j];
  *(f32x4*)(out + i) = o;
}

__global__ __launch_bounds__(256) void reduce4(const u16* __restrict__ P0, const u16* __restrict__ P1,
                                               const u16* __restrict__ P2, const u16* __restrict__ P3,
                                               const float* __restrict__ bias, const float* __restrict__ res,
                                               float* __restrict__ out){
  size_t i = ((size_t)blockIdx.x*256 + threadIdx.x)*4;
  u16x4 a = *(const u16x4*)(P0 + i);
  u16x4 b = *(const u16x4*)(P1 + i);
  u16x4 c = *(const u16x4*)(P2 + i);
  u16x4 d = *(const u16x4*)(P3 + i);
  f32x4 rv = *(const f32x4*)(res + i);
  f32x4 bv = *(const f32x4*)(bias + (i & 1023));
  f32x4 o;
  #pragma unroll
  for (int j=0;j<4;j++) o[j] = (bf2f(a[j]) + bf2f(b[j])) + (bf2f(c[j]) + bf2f(d[j])) + bv[j] + rv[j];
  *(f32x4*)(out + i) = o;
}

// ---------------- attention: per-(head,chunk) sums of K outer v and K ----------------
__global__ __launch_bounds__(256) void attn_chunksum(const u16* __restrict__ qkv, float* __restrict__ S,
                                                     float* __restrict__ Ks){
  __shared__ float Kf[4096], Vf[4096];
  int c = blockIdx.x, h = blockIdx.y, tid = threadIdx.x;
  int t = tid >> 2, seg = tid & 3, e0 = seg*16;
  size_t rowb = (size_t)(c*64 + t)*3072 + h*64 + e0;
  u16x8 k0 = *(const u16x8*)(qkv + rowb + 1024);
  u16x8 k1 = *(const u16x8*)(qkv + rowb + 1032);
  u16x8 v0 = *(const u16x8*)(qkv + rowb + 2048);
  u16x8 v1 = *(const u16x8*)(qkv + rowb + 2056);
  #pragma unroll
  for (int i=0;i<8;i++){
    Kf[t*64 + e0 + i]     = elup(bf2f(k0[i]));
    Kf[t*64 + e0 + 8 + i] = elup(bf2f(k1[i]));
    Vf[t*64 + e0 + i]     = bf2f(v0[i]);
    Vf[t*64 + e0 + 8 + i] = bf2f(v1[i]);
  }
  __syncthreads();
  int d = t;
  f32x4 s4[4] = {};
  float ks = 0.f;
  for (int tt=0; tt<64; tt++){
    float kd = Kf[tt*64 + d];
    ks += kd;
    const f32x4* vp = (const f32x4*)&Vf[tt*64 + e0];
    s4[0] += kd*vp[0]; s4[1] += kd*vp[1]; s4[2] += kd*vp[2]; s4[3] += kd*vp[3];
  }
  size_t base = (size_t)(h*32 + c)*4096 + (size_t)d*64 + e0;
  f32x4* so = (f32x4*)(S + base);
  so[0]=s4[0]; so[1]=s4[1]; so[2]=s4[2]; so[3]=s4[3];
  if (seg == 0) Ks[(size_t)(h*32 + c)*64 + d] = ks;
}

// ---------------- attention: exclusive prefix over chunks (per head, element-parallel) ----------------
__global__ __launch_bounds__(256) void attn_prefix(float* __restrict__ S, float* __restrict__ Ks){
  int g = blockIdx.x, h = blockIdx.y, tid = threadIdx.x;
  size_t hb = (size_t)h * 32 * 4096;
  int idx = g*256 + tid;
  float run = 0.f;
  for (int c=0; c<32; c++){
    size_t p = hb + (size_t)c*4096 + idx;
    float v = S[p]; S[p] = run; run += v;
  }
  if (g == 0 && tid < 64){
    float r2 = 0.f;
    for (int c=0; c<32; c++){
      size_t p = (size_t)(h*32 + c)*64 + tid;
      float v = Ks[p]; Ks[p] = r2; r2 += v;
    }
  }
}

// ---------------- attention: O = Q*S_prev + tril(Q K^T) V, den = Q*(k_prev + cumsum K) ----------------
__global__ __launch_bounds__(256) void attn_out(const u16* __restrict__ qkv, const float* __restrict__ S,
                                                const float* __restrict__ Ks, u16* __restrict__ o){
  __shared__ float BufA[4096]; // Q, then A = masked QK^T
  __shared__ float BufB[4096]; // K, then V
  __shared__ float BufC[4096]; // S_prev
  __shared__ float kp[64];
  int c = blockIdx.x, h = blockIdx.y, tid = threadIdx.x;
  int t = tid >> 2, seg = tid & 3, e0 = seg*16;

  size_t rowb = (size_t)(c*64 + t)*3072 + h*64 + e0;
  u16x8 q0 = *(const u16x8*)(qkv + rowb);
  u16x8 q1 = *(const u16x8*)(qkv + rowb + 8);
  u16x8 k0 = *(const u16x8*)(qkv + rowb + 1024);
  u16x8 k1 = *(const u16x8*)(qkv + rowb + 1032);
  u16x8 v0 = *(const u16x8*)(qkv + rowb + 2048);
  u16x8 v1 = *(const u16x8*)(qkv + rowb + 2056);
  #pragma unroll
  for (int i=0;i<8;i++){
    BufA[t*64 + e0 + i]     = elup(bf2f(q0[i]));
    BufA[t*64 + e0 + 8 + i] = elup(bf2f(q1[i]));
    BufB[t*64 + e0 + i]     = elup(bf2f(k0[i]));
    BufB[t*64 + e0 + 8 + i] = elup(bf2f(k1[i]));
  }
  size_t sbase = (size_t)(h*32 + c)*4096;
  {
    const f32x4* sg = (const f32x4*)(S + sbase + tid*16);
    f32x4* sl = (f32x4*)&BufC[tid*16];
    sl[0]=sg[0]; sl[1]=sg[1]; sl[2]=sg[2]; sl[3]=sg[3];
  }
  if (tid < 64) kp[tid] = Ks[(size_t)(h*32 + c)*64 + tid];
  __syncthreads();

  // Q row -> registers (static indexing only)
  f32x4 qv[16];
  {
    const f32x4* qp = (const f32x4*)&BufA[t*64];
    #pragma unroll
    for (int i=0;i<16;i++) qv[i] = qp[i];
  }

  // phase 1a: num = Q * S_prev (this thread's 16 e's), den0 = Q . k_prev
  f32x4 num[4] = {};
  float den = 0.f;
  #pragma unroll
  for (int d=0; d<64; d++){
    float qd = qv[d>>2][d&3];
    den += qd * kp[d];
    const f32x4* sp = (const f32x4*)&BufC[d*64 + e0];
    num[0] += qd*sp[0]; num[1] += qd*sp[1]; num[2] += qd*sp[2]; num[3] += qd*sp[3];
  }

  // phase 1b: a[j] = Q[t] . K[s],  s = seg*16 + j, masked to s<=t
  float a[16];
  #pragma unroll
  for (int j=0;j<16;j++){
    int s = e0 + j;
    const f32x4* kr = (const f32x4*)&BufB[s*64];
    f32x4 ac = {};
    #pragma unroll
    for (int d4=0; d4<16; d4++) ac += qv[d4]*kr[d4];
    float av = ac[0]+ac[1]+ac[2]+ac[3];
    a[j] = (s <= t) ? av : 0.f;
  }
  __syncthreads();   // all Q/K LDS reads done
  #pragma unroll
  for (int j=0;j<16;j++) BufA[t*64 + e0 + j] = a[j];   // A into Q's buffer
  #pragma unroll
  for (int i=0;i<8;i++){                                // V into K's buffer
    BufB[t*64 + e0 + i]     = bf2f(v0[i]);
    BufB[t*64 + e0 + 8 + i] = bf2f(v1[i]);
  }
  __syncthreads();

  // phase 2: num += A[t][s] * V[s][e], den += sum_s A[t][s]
  #pragma unroll 4
  for (int s=0; s<64; s++){
    float av = BufA[t*64 + s];
    den += av;
    const f32x4* vp = (const f32x4*)&BufB[s*64 + e0];
    num[0] += av*vp[0]; num[1] += av*vp[1]; num[2] += av*vp[2]; num[3] += av*vp[3];
  }

  float inv = 1.f/(den + 1e-6f);
  u16x8 w0, w1;
  #pragma unroll
  for (int i=0;i<8;i++){
    w0[i] = f2bf(num[i>>2][i&3]*inv);
    w1[i] = f2bf(num[2 + (i>>2)][i&3]*inv);
  }
  size_t ob = (size_t)(c*64 + t)*1024 + h*64 + e0;
  *(u16x8*)(o + ob)     = w0;
  *(u16x8*)(o + ob + 8) = w1;
}

// ---------------- launch ----------------
extern "C" void kernel_launch(void* const* d_in, const int* in_sizes, int n_in,
                              void* d_out, int out_size, void* d_ws, size_t ws_size,
                              hipStream_t stream) {
  (void)in_sizes; (void)n_in; (void)out_size; (void)ws_size;
  const float* x     = (const float*)d_in[0];
  const float* qkv_w = (const float*)d_in[1];
  const float* qkv_b = (const float*)d_in[2];
  const float* out_w = (const float*)d_in[3];
  const float* out_b = (const float*)d_in[4];
  const float* ln1_g = (const float*)d_in[5];
  const float* ln1_b = (const float*)d_in[6];
  const float* ln2_g = (const float*)d_in[7];
  const float* ln2_b = (const float*)d_in[8];
  const float* w1    = (const float*)d_in[9];
  const float* b1    = (const float*)d_in[10];
  const float* w2    = (const float*)d_in[11];
  const float* b2    = (const float*)d_in[12];

  char* ws = (char*)d_ws;
  // lifetimes: wT_qkv dead after qkv GEMM; wT_out dead after out-proj; wT_w1 dead after MLP1;
  //            qkv dead after attn_out; Ssum dead after attn_out; h1/o dead after out-proj;
  //            h2 dead after MLP1. Partial buffers reuse exactly those dead regions.
  u16*   wT_qkv = (u16*)  (ws);              // [0, 6291456)        3072x1024 bf16
  u16*   wT_out = (u16*)  (ws +  6291456);   // [6291456, 8388608)  1024x1024 bf16
  u16*   wT_w1  = (u16*)  (ws +  8388608);   // [8388608, 16777216) 4096x1024 bf16
  u16*   wT_w2  = (u16*)  (ws + 16777216);   // [16777216, 25165824) 1024x4096 bf16
  u16*   h1     = (u16*)  (ws + 25165824);   // [25165824, 29360128) 2048x1024 bf16 (reused as o)
  u16*   qkv    = (u16*)  (ws + 29360128);   // [29360128, 41943040) 2048x3072 bf16 (a1 spills into Ssum)
  float* Ssum   = (float*)(ws + 41943040);   // [41943040, 50331648) 16*32*4096 f32
  float* ksum   = (float*)(ws + 50331648);   // 16*32*64 f32
  float* x2     = (float*)(ws + 50462720);   // [50462720, 58851328) 2048x1024 f32
  u16*   h2     = (u16*)  (ws + 58851328);   // [58851328, 63045632) 2048x1024 bf16
  u16*   o      = h1;
  u16*   a1     = qkv;                        // 2048x4096 bf16
  // out-proj split-2 partials (2048x1024 bf16 each): over dead wT_qkv and dead qkv
  u16*   Pa0    = (u16*)(ws);                         // [0, 4194304)
  u16*   Pa1    = (u16*)(ws + 29360128);              // [29360128, 33554432) — dead qkv; a1 written later
  size_t PaStride = (size_t)(29360128) / 2;           // elements (u16): Pa1 = Pa0 + stride
  // MLP2 split-4 partials: over dead wT_qkv+wT_out+wT_w1 = [0, 16777216)
  u16*   Pm0    = (u16*)(ws);
  u16*   Pm1    = (u16*)(ws +  4194304);
  u16*   Pm2    = (u16*)(ws +  8388608);
  u16*   Pm3    = (u16*)(ws + 12582912);
  size_t PmStride = 2097152;                          // elements
  float* outp   = (float*)d_out;

  TD t0{qkv_w, wT_qkv, 1024, 3072,  96, 3072};
  TD t1{out_w, wT_out, 1024, 1024,  32, 1024};
  TD t2{w1,    wT_w1,  1024, 4096, 128, 4096};
  TD t3{w2,    wT_w2,  4096, 1024,  32, 4096};
  transpose4<<<12288, dim3(32,8), 0, stream>>>(t0, t1, t2, t3);

  ln_f32<<<2048, 256, 0, stream>>>(x, ln1_g, ln1_b, h1);
  gemm_bt<0><<<dim3(16, 24, 1), 256, 0, stream>>>(h1, wT_qkv, qkv_b, nullptr, qkv, 3072, 1024, 0);

  attn_chunksum<<<dim3(32, 16), 256, 0, stream>>>(qkv, Ssum, ksum);
  attn_prefix  <<<dim3(16, 16), 256, 0, stream>>>(Ssum, ksum);
  attn_out     <<<dim3(32, 16), 256, 0, stream>>>(qkv, Ssum, ksum, o);

  // out-proj: split-K x2 -> partials -> reduce(+out_b +x) -> x2 (f32)
  gemm_bt<3><<<dim3(16, 8, 2), 256, 0, stream>>>(o, wT_out, nullptr, nullptr, Pa0, 1024, 1024, PaStride);
  reduce2<<<2048, 256, 0, stream>>>(Pa0, Pa1, out_b, x, x2);

  ln_f32<<<2048, 256, 0, stream>>>(x2, ln2_g, ln2_b, h2);
  gemm_bt<1><<<dim3(16, 32, 1), 256, 0, stream>>>(h2, wT_w1, b1, nullptr, a1, 4096, 1024, 0);

  // MLP2: split-K x4 -> partials -> reduce(+b2 +x2) -> d_out (f32)
  gemm_bt<3><<<dim3(16, 8, 4), 256, 0, stream>>>(a1, wT_w2, nullptr, nullptr, Pm0, 1024, 4096, PmStride);
  reduce4<<<2048, 256, 0, stream>>>(Pm0, Pm1, Pm2, Pm3, b2, x2, outp);
}

// Round 8
// 146.183 us; speedup vs baseline: 1.7587x; 1.2235x over previous
//
#include <hip/hip_runtime.h>

typedef unsigned short u16;
typedef __bf16 bf16x8 __attribute__((ext_vector_type(8)));
typedef float f32x4 __attribute__((ext_vector_type(4)));
typedef unsigned short u16x8 __attribute__((ext_vector_type(8)));
typedef unsigned short u16x4 __attribute__((ext_vector_type(4)));

__device__ __forceinline__ float bf2f(u16 u){
  union { unsigned i; float f; } v; v.i = ((unsigned)u) << 16; return v.f;
}
__device__ __forceinline__ u16 f2bf(float f){
  union { float f; unsigned i; } v; v.f = f;
  unsigned r = v.i + 0x7FFFu + ((v.i >> 16) & 1u);
  return (u16)(r >> 16);
}
// elu(x)+1:  x>0 -> x+1 ; x<=0 -> exp(x)
__device__ __forceinline__ float elup(float x){ return x > 0.f ? x + 1.f : expf(x); }

__device__ __forceinline__ void gload_lds16(const void* gsrc, void* ldst){
  __builtin_amdgcn_global_load_lds(
      (__attribute__((address_space(1))) void*)(unsigned long long)gsrc,
      (__attribute__((address_space(3))) void*)(unsigned)(unsigned long long)ldst,
      16, 0, 0);
}

// ---------------- fused transpose+cast: 4 matrices, in[R][Cc] f32 -> out[Cc][R] bf16 ----------------
struct TD { const float* in; u16* out; int R, Cc, cx, ntiles; };

__global__ __launch_bounds__(256) void transpose4(TD d0, TD d1, TD d2, TD d3){
  __shared__ u16 tile[32][33];
  int b = blockIdx.x;
  TD d;
  if (b < d0.ntiles) d = d0;
  else { b -= d0.ntiles;
    if (b < d1.ntiles) d = d1;
    else { b -= d1.ntiles;
      if (b < d2.ntiles) d = d2;
      else { b -= d2.ntiles; d = d3; } } }
  int c0 = (b % d.cx) * 32, r0 = (b / d.cx) * 32;
  int tx = threadIdx.x, ty = threadIdx.y; // 32 x 8
  #pragma unroll
  for (int i=0;i<4;i++)
    tile[ty + i*8][tx] = f2bf(d.in[(size_t)(r0 + ty + i*8)*d.Cc + c0 + tx]);
  __syncthreads();
  #pragma unroll
  for (int i=0;i<4;i++)
    d.out[(size_t)(c0 + ty + i*8)*d.R + r0 + tx] = tile[tx][ty + i*8];
}

// ---------------- LayerNorm (row of 1024): f32 in, bf16 out ----------------
__global__ __launch_bounds__(256) void ln_f32(const float* __restrict__ x, const float* __restrict__ g,
                                              const float* __restrict__ b, u16* __restrict__ y){
  int row = blockIdx.x, tid = threadIdx.x;
  size_t base = (size_t)row*1024 + tid*4;
  f32x4 xv = *(const f32x4*)(x + base);
  float v0=xv[0], v1=xv[1], v2=xv[2], v3=xv[3];
  float s  = v0+v1+v2+v3;
  float s2 = v0*v0+v1*v1+v2*v2+v3*v3;
  #pragma unroll
  for (int off=32; off>0; off>>=1){ s += __shfl_xor(s, off); s2 += __shfl_xor(s2, off); }
  __shared__ float ls[4], ls2[4];
  if ((tid & 63) == 0){ ls[tid>>6] = s; ls2[tid>>6] = s2; }
  __syncthreads();
  float ts = ls[0]+ls[1]+ls[2]+ls[3];
  float ts2 = ls2[0]+ls2[1]+ls2[2]+ls2[3];
  float mean = ts*(1.f/1024.f);
  float var  = ts2*(1.f/1024.f) - mean*mean;
  float rstd = rsqrtf(var + 1e-5f);
  f32x4 gv = *(const f32x4*)(g + tid*4);
  f32x4 bv = *(const f32x4*)(b + tid*4);
  u16x4 ov;
  ov[0]=f2bf((v0-mean)*rstd*gv[0]+bv[0]);
  ov[1]=f2bf((v1-mean)*rstd*gv[1]+bv[1]);
  ov[2]=f2bf((v2-mean)*rstd*gv[2]+bv[2]);
  ov[3]=f2bf((v3-mean)*rstd*gv[3]+bv[3]);
  *(u16x4*)(y + base) = ov;
}

// ---------------- GEMM: C[M][N] = A[M][K] * BT[N][K]^T (+ bias), fused epilogue ----------------
// Double-buffered LDS (stage t+1 before computing t).
// EPI 0: +bias -> bf16 out.   1: gelu(+bias) -> bf16 out.   2: +bias +f32 residual -> f32 out.
// EPI 3: split-K bf16 PARTIAL out (no bias); gridDim.z = #splits, partial z at out + z*pstride.
template<int EPI>
__global__ __launch_bounds__(256) void gemm_bt(const u16* __restrict__ A, const u16* __restrict__ BT,
                                               const float* __restrict__ bias, const float* __restrict__ res,
                                               void* __restrict__ out, int N, int K, size_t pstride){
  __shared__ u16 As[2][128*32];
  __shared__ u16 Bs[2][128*32];
  int tid = threadIdx.x;
  int w = tid >> 6, lane = tid & 63;
  int m0 = blockIdx.x * 128, n0 = blockIdx.y * 128;
  int Kc = K / gridDim.z;
  int kbase = blockIdx.z * Kc;
  int nt = Kc / 32;

  f32x4 acc[4][4] = {};

  const u16* aSrc = A  + (size_t)(m0 + w*32 + (lane>>2))*K + kbase + (lane&3)*8;
  const u16* bSrc = BT + (size_t)(n0 + w*32 + (lane>>2))*K + kbase + (lane&3)*8;
  int r0 = (w>>1)*64, c0 = (w&1)*64;
  int lrow = lane & 15, lk = (lane>>4)*8;

  {
    u16* aD = As[0] + w*1024;
    u16* bD = Bs[0] + w*1024;
    gload_lds16(aSrc,                aD);
    gload_lds16(aSrc + (size_t)16*K, aD + 512);
    gload_lds16(bSrc,                bD);
    gload_lds16(bSrc + (size_t)16*K, bD + 512);
  }
  __syncthreads();

  int cur = 0;
  for (int t = 0; t < nt; ++t){
    if (t + 1 < nt){
      int k0 = (t+1)*32;
      u16* aD = As[cur^1] + w*1024;
      u16* bD = Bs[cur^1] + w*1024;
      gload_lds16(aSrc + k0,                aD);
      gload_lds16(aSrc + (size_t)16*K + k0, aD + 512);
      gload_lds16(bSrc + k0,                bD);
      gload_lds16(bSrc + (size_t)16*K + k0, bD + 512);
    }
    const u16* Ab = As[cur];
    const u16* Bb = Bs[cur];
    bf16x8 af[4], bfv[4];
    #pragma unroll
    for (int mi=0;mi<4;mi++) af[mi]  = *(const bf16x8*)(Ab + (r0 + mi*16 + lrow)*32 + lk);
    #pragma unroll
    for (int ni=0;ni<4;ni++) bfv[ni] = *(const bf16x8*)(Bb + (c0 + ni*16 + lrow)*32 + lk);
    #pragma unroll
    for (int mi=0;mi<4;mi++)
      #pragma unroll
      for (int ni=0;ni<4;ni++)
        acc[mi][ni] = __builtin_amdgcn_mfma_f32_16x16x32_bf16(af[mi], bfv[ni], acc[mi][ni], 0, 0, 0);
    __syncthreads();
    cur ^= 1;
  }

  int lgr = lane >> 4;
  u16* pout = (EPI == 3) ? ((u16*)out + (size_t)blockIdx.z * pstride) : (u16*)out;
  #pragma unroll
  for (int mi=0;mi<4;mi++){
    #pragma unroll
    for (int j=0;j<4;j++){
      int row = m0 + r0 + mi*16 + lgr*4 + j;
      #pragma unroll
      for (int ni=0;ni<4;ni++){
        int col = n0 + c0 + ni*16 + lrow;
        size_t idx = (size_t)row*N + col;
        if constexpr (EPI == 3){
          pout[idx] = f2bf(acc[mi][ni][j]);
        } else {
          float v = acc[mi][ni][j] + bias[col];
          if constexpr (EPI == 0){
            ((u16*)out)[idx] = f2bf(v);
          } else if constexpr (EPI == 1){
            v = 0.5f * v * (1.f + erff(v * 0.70710678118654752f));
            ((u16*)out)[idx] = f2bf(v);
          } else {
            ((float*)out)[idx] = v + res[idx];
          }
        }
      }
    }
  }
}

// ---------------- split-K reduction: out = sum(partials) + bias + res  (M=2048, N=1024) ----------------
__global__ __launch_bounds__(256) void reduce2(const u16* __restrict__ P0, const u16* __restrict__ P1,
                                               const float* __restrict__ bias, const float* __restrict__ res,
                                               float* __restrict__ out){
  size_t i = ((size_t)blockIdx.x*256 + threadIdx.x)*4;
  u16x4 a = *(const u16x4*)(P0 + i);
  u16x4 b = *(const u16x4*)(P1 + i);
  f32x4 rv = *(const f32x4*)(res + i);
  f32x4 bv = *(const f32x4*)(bias + (i & 1023));
  f32x4 o;
  #pragma unroll
  for (int j=0;j<4;j++) o[j] = bf2f(a[j]) + bf2f(b[j]) + bv[j] + rv[j];
  *(f32x4*)(out + i) = o;
}

__global__ __launch_bounds__(256) void reduce4(const u16* __restrict__ P0, const u16* __restrict__ P1,
                                               const u16* __restrict__ P2, const u16* __restrict__ P3,
                                               const float* __restrict__ bias, const float* __restrict__ res,
                                               float* __restrict__ out){
  size_t i = ((size_t)blockIdx.x*256 + threadIdx.x)*4;
  u16x4 a = *(const u16x4*)(P0 + i);
  u16x4 b = *(const u16x4*)(P1 + i);
  u16x4 c = *(const u16x4*)(P2 + i);
  u16x4 d = *(const u16x4*)(P3 + i);
  f32x4 rv = *(const f32x4*)(res + i);
  f32x4 bv = *(const f32x4*)(bias + (i & 1023));
  f32x4 o;
  #pragma unroll
  for (int j=0;j<4;j++) o[j] = (bf2f(a[j]) + bf2f(b[j])) + (bf2f(c[j]) + bf2f(d[j])) + bv[j] + rv[j];
  *(f32x4*)(out + i) = o;
}

// ---------------- attention: per-(head,chunk) S^T[e][d] = sum_t V[t][e]*K'[t][d], Ks[d]=sum_t K'[t][d] ----------------
// MFMA version: KT/VT staged transposed in LDS (k-dim = t), one 64x64x64 matmul per block.
__global__ __launch_bounds__(256) void attn_chunksum(const u16* __restrict__ qkv, float* __restrict__ S,
                                                     float* __restrict__ Ks){
  __shared__ u16 KT[64*72];  // [d][t] bf16, elup'd
  __shared__ u16 VT[64*72];  // [e][t] bf16 (raw)
  int c = blockIdx.x, h = blockIdx.y, tid = threadIdx.x;
  int t = tid >> 2, seg = tid & 3, e0 = seg*16;
  size_t rowb = (size_t)(c*64 + t)*3072 + h*64 + e0;
  u16x8 k0 = *(const u16x8*)(qkv + rowb + 1024);
  u16x8 k1 = *(const u16x8*)(qkv + rowb + 1032);
  u16x8 v0 = *(const u16x8*)(qkv + rowb + 2048);
  u16x8 v1 = *(const u16x8*)(qkv + rowb + 2056);
  #pragma unroll
  for (int i=0;i<8;i++){
    KT[(e0 + i)*72 + t]     = f2bf(elup(bf2f(k0[i])));
    KT[(e0 + 8 + i)*72 + t] = f2bf(elup(bf2f(k1[i])));
    VT[(e0 + i)*72 + t]     = v0[i];
    VT[(e0 + 8 + i)*72 + t] = v1[i];
  }
  __syncthreads();

  int w = tid >> 6, lane = tid & 63;
  int lr = lane & 15, lk = (lane>>4)*8, g = lane >> 4, cl = lane & 15;
  bf16x8 av_[2];
  #pragma unroll
  for (int kk=0;kk<2;kk++) av_[kk] = *(const bf16x8*)(VT + (w*16 + lr)*72 + kk*32 + lk);
  f32x4 acc[4] = {};
  #pragma unroll
  for (int di=0;di<4;di++){
    #pragma unroll
    for (int kk=0;kk<2;kk++){
      bf16x8 bk = *(const bf16x8*)(KT + (di*16 + lr)*72 + kk*32 + lk);
      acc[di] = __builtin_amdgcn_mfma_f32_16x16x32_bf16(av_[kk], bk, acc[di], 0, 0, 0);
    }
  }
  size_t base = (size_t)(h*32 + c)*4096;
  #pragma unroll
  for (int di=0;di<4;di++)
    #pragma unroll
    for (int j=0;j<4;j++)
      S[base + (size_t)(w*16 + g*4 + j)*64 + di*16 + cl] = acc[di][j];

  // ks[d] = sum_t KT[d][t]; thread (d=t, t-range = e0..e0+15)
  float s = 0.f;
  #pragma unroll
  for (int i=0;i<16;i++) s += bf2f(KT[t*72 + e0 + i]);
  s += __shfl_xor(s, 1); s += __shfl_xor(s, 2);
  if (seg == 0) Ks[(size_t)(h*32 + c)*64 + t] = s;
}

// ---------------- attention: exclusive prefix over chunks (per head, element-parallel) ----------------
__global__ __launch_bounds__(256) void attn_prefix(float* __restrict__ S, float* __restrict__ Ks){
  int g = blockIdx.x, h = blockIdx.y, tid = threadIdx.x;
  size_t hb = (size_t)h * 32 * 4096;
  int idx = g*256 + tid;
  float run = 0.f;
  for (int c=0; c<32; c++){
    size_t p = hb + (size_t)c*4096 + idx;
    float v = S[p]; S[p] = run; run += v;
  }
  if (g == 0 && tid < 64){
    float r2 = 0.f;
    for (int c=0; c<32; c++){
      size_t p = (size_t)(h*32 + c)*64 + tid;
      float v = Ks[p]; Ks[p] = r2; r2 += v;
    }
  }
}

// ---------------- attention: O = Q*S_prev^T + tril(QK^T)V, den = Q*kp + rowsum(A); MFMA version ----------------
__global__ __launch_bounds__(256) void attn_out(const u16* __restrict__ qkv, const float* __restrict__ S,
                                                const float* __restrict__ Ks, u16* __restrict__ o){
  __shared__ u16 Qs [64*72];  // [t][d] bf16, elup'd
  __shared__ u16 Ksh[64*72];  // [s][d] bf16, elup'd
  __shared__ u16 VT [64*72];  // [e][s] bf16 (raw)
  __shared__ u16 SpT[64*72];  // [e][d] bf16 (S_prev^T)
  __shared__ u16 Am [64*72];  // [t][s] masked QK^T, bf16
  __shared__ float kp[64], den[64];
  int c = blockIdx.x, h = blockIdx.y, tid = threadIdx.x;
  int t = tid >> 2, seg = tid & 3, e0 = seg*16;

  size_t rowb = (size_t)(c*64 + t)*3072 + h*64 + e0;
  u16x8 q0 = *(const u16x8*)(qkv + rowb);
  u16x8 q1 = *(const u16x8*)(qkv + rowb + 8);
  u16x8 k0 = *(const u16x8*)(qkv + rowb + 1024);
  u16x8 k1 = *(const u16x8*)(qkv + rowb + 1032);
  u16x8 v0 = *(const u16x8*)(qkv + rowb + 2048);
  u16x8 v1 = *(const u16x8*)(qkv + rowb + 2056);
  #pragma unroll
  for (int i=0;i<8;i++){
    Qs [t*72 + e0 + i]     = f2bf(elup(bf2f(q0[i])));
    Qs [t*72 + e0 + 8 + i] = f2bf(elup(bf2f(q1[i])));
    Ksh[t*72 + e0 + i]     = f2bf(elup(bf2f(k0[i])));
    Ksh[t*72 + e0 + 8 + i] = f2bf(elup(bf2f(k1[i])));
    VT [(e0 + i)*72 + t]     = v0[i];
    VT [(e0 + 8 + i)*72 + t] = v1[i];
  }
  size_t sbase = (size_t)(h*32 + c)*4096;
  {
    const f32x4* sp = (const f32x4*)(S + sbase + (size_t)t*64 + e0);
    #pragma unroll
    for (int qd=0;qd<4;qd++){
      f32x4 v = sp[qd];
      #pragma unroll
      for (int j=0;j<4;j++) SpT[t*72 + e0 + qd*4 + j] = f2bf(v[j]);
    }
  }
  if (tid < 64) kp[tid] = Ks[(size_t)(h*32 + c)*64 + tid];
  __syncthreads();

  int w = tid >> 6, lane = tid & 63;
  int lr = lane & 15, lk = (lane>>4)*8, g = lane >> 4, cl = lane & 15;

  bf16x8 aq[2];
  #pragma unroll
  for (int kk=0;kk<2;kk++) aq[kk] = *(const bf16x8*)(Qs + (w*16 + lr)*72 + kk*32 + lk);

  // acc = Q * S_prev^T  (output [t][e])
  f32x4 acc[4] = {};
  #pragma unroll
  for (int ni=0;ni<4;ni++){
    #pragma unroll
    for (int kk=0;kk<2;kk++){
      bf16x8 bs = *(const bf16x8*)(SpT + (ni*16 + lr)*72 + kk*32 + lk);
      acc[ni] = __builtin_amdgcn_mfma_f32_16x16x32_bf16(aq[kk], bs, acc[ni], 0, 0, 0);
    }
  }
  // A = tril(Q K^T)  -> bf16 LDS
  #pragma unroll
  for (int si=0;si<4;si++){
    f32x4 qk = {};
    #pragma unroll
    for (int kk=0;kk<2;kk++){
      bf16x8 bk = *(const bf16x8*)(Ksh + (si*16 + lr)*72 + kk*32 + lk);
      qk = __builtin_amdgcn_mfma_f32_16x16x32_bf16(aq[kk], bk, qk, 0, 0, 0);
    }
    #pragma unroll
    for (int j=0;j<4;j++){
      int rowt = w*16 + g*4 + j;
      int scol = si*16 + cl;
      Am[rowt*72 + scol] = f2bf((scol <= rowt) ? qk[j] : 0.f);
    }
  }
  __syncthreads();

  // den[t] = rowsum(A[t]) + Q[t].kp  (thread-mapped, shfl over 4 segs)
  {
    float dsum = 0.f;
    #pragma unroll
    for (int i=0;i<16;i++) dsum += bf2f(Am[t*72 + e0 + i]);
    #pragma unroll
    for (int i=0;i<16;i++) dsum += bf2f(Qs[t*72 + e0 + i]) * kp[e0 + i];
    dsum += __shfl_xor(dsum, 1); dsum += __shfl_xor(dsum, 2);
    if (seg == 0) den[t] = dsum;
  }
  // acc += A * V  (A [t][s] k=s; VT rows e, k=s)
  {
    bf16x8 aa[2];
    #pragma unroll
    for (int kk=0;kk<2;kk++) aa[kk] = *(const bf16x8*)(Am + (w*16 + lr)*72 + kk*32 + lk);
    #pragma unroll
    for (int ni=0;ni<4;ni++){
      #pragma unroll
      for (int kk=0;kk<2;kk++){
        bf16x8 bv = *(const bf16x8*)(VT + (ni*16 + lr)*72 + kk*32 + lk);
        acc[ni] = __builtin_amdgcn_mfma_f32_16x16x32_bf16(aa[kk], bv, acc[ni], 0, 0, 0);
      }
    }
  }
  __syncthreads();

  #pragma unroll
  for (int j=0;j<4;j++){
    int rowt = w*16 + g*4 + j;
    float inv = 1.f/(den[rowt] + 1e-6f);
    #pragma unroll
    for (int ni=0;ni<4;ni++)
      o[(size_t)(c*64 + rowt)*1024 + h*64 + ni*16 + cl] = f2bf(acc[ni][j]*inv);
  }
}

// ---------------- launch ----------------
extern "C" void kernel_launch(void* const* d_in, const int* in_sizes, int n_in,
                              void* d_out, int out_size, void* d_ws, size_t ws_size,
                              hipStream_t stream) {
  (void)in_sizes; (void)n_in; (void)out_size; (void)ws_size;
  const float* x     = (const float*)d_in[0];
  const float* qkv_w = (const float*)d_in[1];
  const float* qkv_b = (const float*)d_in[2];
  const float* out_w = (const float*)d_in[3];
  const float* out_b = (const float*)d_in[4];
  const float* ln1_g = (const float*)d_in[5];
  const float* ln1_b = (const float*)d_in[6];
  const float* ln2_g = (const float*)d_in[7];
  const float* ln2_b = (const float*)d_in[8];
  const float* w1    = (const float*)d_in[9];
  const float* b1    = (const float*)d_in[10];
  const float* w2    = (const float*)d_in[11];
  const float* b2    = (const float*)d_in[12];

  char* ws = (char*)d_ws;
  u16*   wT_qkv = (u16*)  (ws);              // [0, 6291456)        3072x1024 bf16
  u16*   wT_out = (u16*)  (ws +  6291456);   // [6291456, 8388608)  1024x1024 bf16
  u16*   wT_w1  = (u16*)  (ws +  8388608);   // [8388608, 16777216) 4096x1024 bf16
  u16*   wT_w2  = (u16*)  (ws + 16777216);   // [16777216, 25165824) 1024x4096 bf16
  u16*   h1     = (u16*)  (ws + 25165824);   // [25165824, 29360128) 2048x1024 bf16 (reused as o)
  u16*   qkv    = (u16*)  (ws + 29360128);   // [29360128, 41943040) 2048x3072 bf16 (a1 spills into Ssum)
  float* Ssum   = (float*)(ws + 41943040);   // [41943040, 50331648) 16*32*4096 f32 (stored as S^T per (h,c))
  float* ksum   = (float*)(ws + 50331648);   // 16*32*64 f32
  float* x2     = (float*)(ws + 50462720);   // [50462720, 58851328) 2048x1024 f32
  u16*   h2     = (u16*)  (ws + 58851328);   // [58851328, 63045632) 2048x1024 bf16
  u16*   o      = h1;
  u16*   a1     = qkv;                        // 2048x4096 bf16
  u16*   Pa0    = (u16*)(ws);                         // out-proj split-2 partials
  size_t PaStride = (size_t)(29360128) / 2;           // elements: Pa1 = Pa0 + stride (dead qkv region)
  u16*   Pa1    = (u16*)(ws + 29360128);
  u16*   Pm0    = (u16*)(ws);                         // MLP2 split-4 partials over dead wT regions
  u16*   Pm1    = (u16*)(ws +  4194304);
  u16*   Pm2    = (u16*)(ws +  8388608);
  u16*   Pm3    = (u16*)(ws + 12582912);
  size_t PmStride = 2097152;                          // elements
  float* outp   = (float*)d_out;

  TD t0{qkv_w, wT_qkv, 1024, 3072,  96, 3072};
  TD t1{out_w, wT_out, 1024, 1024,  32, 1024};
  TD t2{w1,    wT_w1,  1024, 4096, 128, 4096};
  TD t3{w2,    wT_w2,  4096, 1024,  32, 4096};
  transpose4<<<12288, dim3(32,8), 0, stream>>>(t0, t1, t2, t3);

  ln_f32<<<2048, 256, 0, stream>>>(x, ln1_g, ln1_b, h1);
  gemm_bt<0><<<dim3(16, 24, 1), 256, 0, stream>>>(h1, wT_qkv, qkv_b, nullptr, qkv, 3072, 1024, 0);

  attn_chunksum<<<dim3(32, 16), 256, 0, stream>>>(qkv, Ssum, ksum);
  attn_prefix  <<<dim3(16, 16), 256, 0, stream>>>(Ssum, ksum);
  attn_out     <<<dim3(32, 16), 256, 0, stream>>>(qkv, Ssum, ksum, o);

  gemm_bt<3><<<dim3(16, 8, 2), 256, 0, stream>>>(o, wT_out, nullptr, nullptr, Pa0, 1024, 1024, PaStride);
  reduce2<<<2048, 256, 0, stream>>>(Pa0, Pa1, out_b, x, x2);

  ln_f32<<<2048, 256, 0, stream>>>(x2, ln2_g, ln2_b, h2);
  gemm_bt<1><<<dim3(16, 32, 1), 256, 0, stream>>>(h2, wT_w1, b1, nullptr, a1, 4096, 1024, 0);

  gemm_bt<3><<<dim3(16, 8, 4), 256, 0, stream>>>(a1, wT_w2, nullptr, nullptr, Pm0, 1024, 4096, PmStride);
  reduce4<<<2048, 256, 0, stream>>>(Pm0, Pm1, Pm2, Pm3, b2, x2, outp);
}

// Round 9
// 142.700 us; speedup vs baseline: 1.8016x; 1.0244x over previous
//
#include <hip/hip_runtime.h>

typedef unsigned short u16;
typedef __bf16 bf16x8 __attribute__((ext_vector_type(8)));
typedef float f32x4 __attribute__((ext_vector_type(4)));
typedef unsigned short u16x8 __attribute__((ext_vector_type(8)));
typedef unsigned short u16x4 __attribute__((ext_vector_type(4)));

__device__ __forceinline__ float bf2f(u16 u){
  union { unsigned i; float f; } v; v.i = ((unsigned)u) << 16; return v.f;
}
__device__ __forceinline__ u16 f2bf(float f){
  union { float f; unsigned i; } v; v.f = f;
  unsigned r = v.i + 0x7FFFu + ((v.i >> 16) & 1u);
  return (u16)(r >> 16);
}
// elu(x)+1:  x>0 -> x+1 ; x<=0 -> exp(x)
__device__ __forceinline__ float elup(float x){ return x > 0.f ? x + 1.f : expf(x); }

__device__ __forceinline__ void gload_lds16(const void* gsrc, void* ldst){
  __builtin_amdgcn_global_load_lds(
      (__attribute__((address_space(1))) void*)(unsigned long long)gsrc,
      (__attribute__((address_space(3))) void*)(unsigned)(unsigned long long)ldst,
      16, 0, 0);
}

// ---------------- fused transpose+cast: 4 matrices, in[R][Cc] f32 -> out[Cc][R] bf16 ----------------
struct TD { const float* in; u16* out; int R, Cc, cx, ntiles; };

__global__ __launch_bounds__(256) void transpose4(TD d0, TD d1, TD d2, TD d3){
  __shared__ u16 tile[32][33];
  int b = blockIdx.x;
  TD d;
  if (b < d0.ntiles) d = d0;
  else { b -= d0.ntiles;
    if (b < d1.ntiles) d = d1;
    else { b -= d1.ntiles;
      if (b < d2.ntiles) d = d2;
      else { b -= d2.ntiles; d = d3; } } }
  int c0 = (b % d.cx) * 32, r0 = (b / d.cx) * 32;
  int tx = threadIdx.x, ty = threadIdx.y; // 32 x 8
  #pragma unroll
  for (int i=0;i<4;i++)
    tile[ty + i*8][tx] = f2bf(d.in[(size_t)(r0 + ty + i*8)*d.Cc + c0 + tx]);
  __syncthreads();
  #pragma unroll
  for (int i=0;i<4;i++)
    d.out[(size_t)(c0 + ty + i*8)*d.R + r0 + tx] = tile[tx][ty + i*8];
}

// ---------------- LayerNorm (row of 1024): f32 in, bf16 out ----------------
__global__ __launch_bounds__(256) void ln_f32(const float* __restrict__ x, const float* __restrict__ g,
                                              const float* __restrict__ b, u16* __restrict__ y){
  int row = blockIdx.x, tid = threadIdx.x;
  size_t base = (size_t)row*1024 + tid*4;
  f32x4 xv = *(const f32x4*)(x + base);
  float v0=xv[0], v1=xv[1], v2=xv[2], v3=xv[3];
  float s  = v0+v1+v2+v3;
  float s2 = v0*v0+v1*v1+v2*v2+v3*v3;
  #pragma unroll
  for (int off=32; off>0; off>>=1){ s += __shfl_xor(s, off); s2 += __shfl_xor(s2, off); }
  __shared__ float ls[4], ls2[4];
  if ((tid & 63) == 0){ ls[tid>>6] = s; ls2[tid>>6] = s2; }
  __syncthreads();
  float ts = ls[0]+ls[1]+ls[2]+ls[3];
  float ts2 = ls2[0]+ls2[1]+ls2[2]+ls2[3];
  float mean = ts*(1.f/1024.f);
  float var  = ts2*(1.f/1024.f) - mean*mean;
  float rstd = rsqrtf(var + 1e-5f);
  f32x4 gv = *(const f32x4*)(g + tid*4);
  f32x4 bv = *(const f32x4*)(b + tid*4);
  u16x4 ov;
  ov[0]=f2bf((v0-mean)*rstd*gv[0]+bv[0]);
  ov[1]=f2bf((v1-mean)*rstd*gv[1]+bv[1]);
  ov[2]=f2bf((v2-mean)*rstd*gv[2]+bv[2]);
  ov[3]=f2bf((v3-mean)*rstd*gv[3]+bv[3]);
  *(u16x4*)(y + base) = ov;
}

// ---------------- fused split-K reduce(+bias+residual) -> x2 (f32) AND LayerNorm -> h2 (bf16) ----------------
__global__ __launch_bounds__(256) void ln2_fused(const u16* __restrict__ P0, const u16* __restrict__ P1,
                                                 const u16* __restrict__ P2, const u16* __restrict__ P3,
                                                 const float* __restrict__ bias, const float* __restrict__ xres,
                                                 const float* __restrict__ g, const float* __restrict__ b,
                                                 float* __restrict__ x2, u16* __restrict__ h2){
  int row = blockIdx.x, tid = threadIdx.x;
  size_t base = (size_t)row*1024 + tid*4;
  u16x4 a0 = *(const u16x4*)(P0 + base);
  u16x4 a1 = *(const u16x4*)(P1 + base);
  u16x4 a2 = *(const u16x4*)(P2 + base);
  u16x4 a3 = *(const u16x4*)(P3 + base);
  f32x4 rv = *(const f32x4*)(xres + base);
  f32x4 bv = *(const f32x4*)(bias + tid*4);
  f32x4 v;
  #pragma unroll
  for (int j=0;j<4;j++) v[j] = (bf2f(a0[j])+bf2f(a1[j])) + (bf2f(a2[j])+bf2f(a3[j])) + bv[j] + rv[j];
  *(f32x4*)(x2 + base) = v;
  float s  = v[0]+v[1]+v[2]+v[3];
  float s2 = v[0]*v[0]+v[1]*v[1]+v[2]*v[2]+v[3]*v[3];
  #pragma unroll
  for (int off=32; off>0; off>>=1){ s += __shfl_xor(s, off); s2 += __shfl_xor(s2, off); }
  __shared__ float ls[4], ls2[4];
  if ((tid & 63) == 0){ ls[tid>>6] = s; ls2[tid>>6] = s2; }
  __syncthreads();
  float ts = ls[0]+ls[1]+ls[2]+ls[3];
  float ts2 = ls2[0]+ls2[1]+ls2[2]+ls2[3];
  float mean = ts*(1.f/1024.f);
  float var  = ts2*(1.f/1024.f) - mean*mean;
  float rstd = rsqrtf(var + 1e-5f);
  f32x4 gv = *(const f32x4*)(g + tid*4);
  f32x4 bb = *(const f32x4*)(b + tid*4);
  u16x4 ov;
  #pragma unroll
  for (int j=0;j<4;j++) ov[j] = f2bf((v[j]-mean)*rstd*gv[j]+bb[j]);
  *(u16x4*)(h2 + base) = ov;
}

// ---------------- GEMM: C[M][N] = A[M][K] * BT[N][K]^T (+ bias), 8 waves/block, dbuf LDS ----------------
// Wave w owns 32x64 sub-tile: rows (w>>1)*32, cols (w&1)*64. Each thread stages one 16B chunk
// of A and one of B per K-step (wave-linear LDS dest for global_load_lds).
// EPI 0: +bias -> bf16 out.   1: gelu(+bias) -> bf16 out.
// EPI 3: split-K bf16 PARTIAL out (no bias); gridDim.z = #splits, partial z at out + z*pstride.
template<int EPI>
__global__ __launch_bounds__(512) void gemm_bt(const u16* __restrict__ A, const u16* __restrict__ BT,
                                               const float* __restrict__ bias, const float* __restrict__ res,
                                               void* __restrict__ out, int N, int K, size_t pstride){
  __shared__ u16 As[2][128*32];
  __shared__ u16 Bs[2][128*32];
  int tid = threadIdx.x;
  int w = tid >> 6, lane = tid & 63;
  int m0 = blockIdx.x * 128, n0 = blockIdx.y * 128;
  int Kc = K / gridDim.z;
  int kbase = blockIdx.z * Kc;
  int nt = Kc / 32;

  f32x4 acc[2][4] = {};

  const u16* aSrc = A  + (size_t)(m0 + w*16 + (lane>>2))*K + kbase + (lane&3)*8;
  const u16* bSrc = BT + (size_t)(n0 + w*16 + (lane>>2))*K + kbase + (lane&3)*8;
  int r0 = (w>>1)*32, c0 = (w&1)*64;
  int lrow = lane & 15, lk = (lane>>4)*8;

  {
    gload_lds16(aSrc, As[0] + w*512);
    gload_lds16(bSrc, Bs[0] + w*512);
  }
  __syncthreads();

  int cur = 0;
  for (int t = 0; t < nt; ++t){
    if (t + 1 < nt){
      int k0 = (t+1)*32;
      gload_lds16(aSrc + k0, As[cur^1] + w*512);
      gload_lds16(bSrc + k0, Bs[cur^1] + w*512);
    }
    const u16* Ab = As[cur];
    const u16* Bb = Bs[cur];
    bf16x8 af[2], bfv[4];
    #pragma unroll
    for (int mi=0;mi<2;mi++) af[mi]  = *(const bf16x8*)(Ab + (r0 + mi*16 + lrow)*32 + lk);
    #pragma unroll
    for (int ni=0;ni<4;ni++) bfv[ni] = *(const bf16x8*)(Bb + (c0 + ni*16 + lrow)*32 + lk);
    #pragma unroll
    for (int mi=0;mi<2;mi++)
      #pragma unroll
      for (int ni=0;ni<4;ni++)
        acc[mi][ni] = __builtin_amdgcn_mfma_f32_16x16x32_bf16(af[mi], bfv[ni], acc[mi][ni], 0, 0, 0);
    __syncthreads();
    cur ^= 1;
  }

  int lgr = lane >> 4;
  u16* pout = (EPI == 3) ? ((u16*)out + (size_t)blockIdx.z * pstride) : (u16*)out;
  #pragma unroll
  for (int mi=0;mi<2;mi++){
    #pragma unroll
    for (int j=0;j<4;j++){
      int row = m0 + r0 + mi*16 + lgr*4 + j;
      #pragma unroll
      for (int ni=0;ni<4;ni++){
        int col = n0 + c0 + ni*16 + lrow;
        size_t idx = (size_t)row*N + col;
        if constexpr (EPI == 3){
          pout[idx] = f2bf(acc[mi][ni][j]);
        } else {
          float v = acc[mi][ni][j] + bias[col];
          if constexpr (EPI == 0){
            ((u16*)out)[idx] = f2bf(v);
          } else {
            v = 0.5f * v * (1.f + erff(v * 0.70710678118654752f));
            ((u16*)out)[idx] = f2bf(v);
          }
        }
      }
    }
  }
}

// ---------------- split-K reduction: out = sum(4 partials) + bias + res (f32 out) ----------------
__global__ __launch_bounds__(256) void reduce4(const u16* __restrict__ P0, const u16* __restrict__ P1,
                                               const u16* __restrict__ P2, const u16* __restrict__ P3,
                                               const float* __restrict__ bias, const float* __restrict__ res,
                                               float* __restrict__ out){
  size_t i = ((size_t)blockIdx.x*256 + threadIdx.x)*4;
  u16x4 a = *(const u16x4*)(P0 + i);
  u16x4 b = *(const u16x4*)(P1 + i);
  u16x4 c = *(const u16x4*)(P2 + i);
  u16x4 d = *(const u16x4*)(P3 + i);
  f32x4 rv = *(const f32x4*)(res + i);
  f32x4 bv = *(const f32x4*)(bias + (i & 1023));
  f32x4 o;
  #pragma unroll
  for (int j=0;j<4;j++) o[j] = (bf2f(a[j]) + bf2f(b[j])) + (bf2f(c[j]) + bf2f(d[j])) + bv[j] + rv[j];
  *(f32x4*)(out + i) = o;
}

// ---------------- attention: per-(head,chunk) S^T[e][d] = sum_t V[t][e]*K'[t][d], Ks[d]=sum_t K'[t][d] ----------------
__global__ __launch_bounds__(256) void attn_chunksum(const u16* __restrict__ qkv, float* __restrict__ S,
                                                     float* __restrict__ Ks){
  __shared__ u16 KT[64*72];  // [d][t] bf16, elup'd
  __shared__ u16 VT[64*72];  // [e][t] bf16 (raw)
  int c = blockIdx.x, h = blockIdx.y, tid = threadIdx.x;
  int t = tid >> 2, seg = tid & 3, e0 = seg*16;
  size_t rowb = (size_t)(c*64 + t)*3072 + h*64 + e0;
  u16x8 k0 = *(const u16x8*)(qkv + rowb + 1024);
  u16x8 k1 = *(const u16x8*)(qkv + rowb + 1032);
  u16x8 v0 = *(const u16x8*)(qkv + rowb + 2048);
  u16x8 v1 = *(const u16x8*)(qkv + rowb + 2056);
  #pragma unroll
  for (int i=0;i<8;i++){
    KT[(e0 + i)*72 + t]     = f2bf(elup(bf2f(k0[i])));
    KT[(e0 + 8 + i)*72 + t] = f2bf(elup(bf2f(k1[i])));
    VT[(e0 + i)*72 + t]     = v0[i];
    VT[(e0 + 8 + i)*72 + t] = v1[i];
  }
  __syncthreads();

  int w = tid >> 6, lane = tid & 63;
  int lr = lane & 15, lk = (lane>>4)*8, g = lane >> 4, cl = lane & 15;
  bf16x8 av_[2];
  #pragma unroll
  for (int kk=0;kk<2;kk++) av_[kk] = *(const bf16x8*)(VT + (w*16 + lr)*72 + kk*32 + lk);
  f32x4 acc[4] = {};
  #pragma unroll
  for (int di=0;di<4;di++){
    #pragma unroll
    for (int kk=0;kk<2;kk++){
      bf16x8 bk = *(const bf16x8*)(KT + (di*16 + lr)*72 + kk*32 + lk);
      acc[di] = __builtin_amdgcn_mfma_f32_16x16x32_bf16(av_[kk], bk, acc[di], 0, 0, 0);
    }
  }
  size_t base = (size_t)(h*32 + c)*4096;
  #pragma unroll
  for (int di=0;di<4;di++)
    #pragma unroll
    for (int j=0;j<4;j++)
      S[base + (size_t)(w*16 + g*4 + j)*64 + di*16 + cl] = acc[di][j];

  float s = 0.f;
  #pragma unroll
  for (int i=0;i<16;i++) s += bf2f(KT[t*72 + e0 + i]);
  s += __shfl_xor(s, 1); s += __shfl_xor(s, 2);
  if (seg == 0) Ks[(size_t)(h*32 + c)*64 + t] = s;
}

// ---------------- attention: exclusive prefix over chunks (per head, element-parallel) ----------------
__global__ __launch_bounds__(256) void attn_prefix(float* __restrict__ S, float* __restrict__ Ks){
  int g = blockIdx.x, h = blockIdx.y, tid = threadIdx.x;
  size_t hb = (size_t)h * 32 * 4096;
  int idx = g*256 + tid;
  float run = 0.f;
  for (int c=0; c<32; c++){
    size_t p = hb + (size_t)c*4096 + idx;
    float v = S[p]; S[p] = run; run += v;
  }
  if (g == 0 && tid < 64){
    float r2 = 0.f;
    for (int c=0; c<32; c++){
      size_t p = (size_t)(h*32 + c)*64 + tid;
      float v = Ks[p]; Ks[p] = r2; r2 += v;
    }
  }
}

// ---------------- attention: O = Q*S_prev^T + tril(QK^T)V, den = Q*kp + rowsum(A); MFMA ----------------
__global__ __launch_bounds__(256) void attn_out(const u16* __restrict__ qkv, const float* __restrict__ S,
                                                const float* __restrict__ Ks, u16* __restrict__ o){
  __shared__ u16 Qs [64*72];
  __shared__ u16 Ksh[64*72];
  __shared__ u16 VT [64*72];
  __shared__ u16 SpT[64*72];
  __shared__ u16 Am [64*72];
  __shared__ float kp[64], den[64];
  int c = blockIdx.x, h = blockIdx.y, tid = threadIdx.x;
  int t = tid >> 2, seg = tid & 3, e0 = seg*16;

  size_t rowb = (size_t)(c*64 + t)*3072 + h*64 + e0;
  u16x8 q0 = *(const u16x8*)(qkv + rowb);
  u16x8 q1 = *(const u16x8*)(qkv + rowb + 8);
  u16x8 k0 = *(const u16x8*)(qkv + rowb + 1024);
  u16x8 k1 = *(const u16x8*)(qkv + rowb + 1032);
  u16x8 v0 = *(const u16x8*)(qkv + rowb + 2048);
  u16x8 v1 = *(const u16x8*)(qkv + rowb + 2056);
  #pragma unroll
  for (int i=0;i<8;i++){
    Qs [t*72 + e0 + i]     = f2bf(elup(bf2f(q0[i])));
    Qs [t*72 + e0 + 8 + i] = f2bf(elup(bf2f(q1[i])));
    Ksh[t*72 + e0 + i]     = f2bf(elup(bf2f(k0[i])));
    Ksh[t*72 + e0 + 8 + i] = f2bf(elup(bf2f(k1[i])));
    VT [(e0 + i)*72 + t]     = v0[i];
    VT [(e0 + 8 + i)*72 + t] = v1[i];
  }
  size_t sbase = (size_t)(h*32 + c)*4096;
  {
    const f32x4* sp = (const f32x4*)(S + sbase + (size_t)t*64 + e0);
    #pragma unroll
    for (int qd=0;qd<4;qd++){
      f32x4 v = sp[qd];
      #pragma unroll
      for (int j=0;j<4;j++) SpT[t*72 + e0 + qd*4 + j] = f2bf(v[j]);
    }
  }
  if (tid < 64) kp[tid] = Ks[(size_t)(h*32 + c)*64 + tid];
  __syncthreads();

  int w = tid >> 6, lane = tid & 63;
  int lr = lane & 15, lk = (lane>>4)*8, g = lane >> 4, cl = lane & 15;

  bf16x8 aq[2];
  #pragma unroll
  for (int kk=0;kk<2;kk++) aq[kk] = *(const bf16x8*)(Qs + (w*16 + lr)*72 + kk*32 + lk);

  f32x4 acc[4] = {};
  #pragma unroll
  for (int ni=0;ni<4;ni++){
    #pragma unroll
    for (int kk=0;kk<2;kk++){
      bf16x8 bs = *(const bf16x8*)(SpT + (ni*16 + lr)*72 + kk*32 + lk);
      acc[ni] = __builtin_amdgcn_mfma_f32_16x16x32_bf16(aq[kk], bs, acc[ni], 0, 0, 0);
    }
  }
  #pragma unroll
  for (int si=0;si<4;si++){
    f32x4 qk = {};
    #pragma unroll
    for (int kk=0;kk<2;kk++){
      bf16x8 bk = *(const bf16x8*)(Ksh + (si*16 + lr)*72 + kk*32 + lk);
      qk = __builtin_amdgcn_mfma_f32_16x16x32_bf16(aq[kk], bk, qk, 0, 0, 0);
    }
    #pragma unroll
    for (int j=0;j<4;j++){
      int rowt = w*16 + g*4 + j;
      int scol = si*16 + cl;
      Am[rowt*72 + scol] = f2bf((scol <= rowt) ? qk[j] : 0.f);
    }
  }
  __syncthreads();

  {
    float dsum = 0.f;
    #pragma unroll
    for (int i=0;i<16;i++) dsum += bf2f(Am[t*72 + e0 + i]);
    #pragma unroll
    for (int i=0;i<16;i++) dsum += bf2f(Qs[t*72 + e0 + i]) * kp[e0 + i];
    dsum += __shfl_xor(dsum, 1); dsum += __shfl_xor(dsum, 2);
    if (seg == 0) den[t] = dsum;
  }
  {
    bf16x8 aa[2];
    #pragma unroll
    for (int kk=0;kk<2;kk++) aa[kk] = *(const bf16x8*)(Am + (w*16 + lr)*72 + kk*32 + lk);
    #pragma unroll
    for (int ni=0;ni<4;ni++){
      #pragma unroll
      for (int kk=0;kk<2;kk++){
        bf16x8 bv = *(const bf16x8*)(VT + (ni*16 + lr)*72 + kk*32 + lk);
        acc[ni] = __builtin_amdgcn_mfma_f32_16x16x32_bf16(aa[kk], bv, acc[ni], 0, 0, 0);
      }
    }
  }
  __syncthreads();

  #pragma unroll
  for (int j=0;j<4;j++){
    int rowt = w*16 + g*4 + j;
    float inv = 1.f/(den[rowt] + 1e-6f);
    #pragma unroll
    for (int ni=0;ni<4;ni++)
      o[(size_t)(c*64 + rowt)*1024 + h*64 + ni*16 + cl] = f2bf(acc[ni][j]*inv);
  }
}

// ---------------- launch ----------------
extern "C" void kernel_launch(void* const* d_in, const int* in_sizes, int n_in,
                              void* d_out, int out_size, void* d_ws, size_t ws_size,
                              hipStream_t stream) {
  (void)in_sizes; (void)n_in; (void)out_size; (void)ws_size;
  const float* x     = (const float*)d_in[0];
  const float* qkv_w = (const float*)d_in[1];
  const float* qkv_b = (const float*)d_in[2];
  const float* out_w = (const float*)d_in[3];
  const float* out_b = (const float*)d_in[4];
  const float* ln1_g = (const float*)d_in[5];
  const float* ln1_b = (const float*)d_in[6];
  const float* ln2_g = (const float*)d_in[7];
  const float* ln2_b = (const float*)d_in[8];
  const float* w1    = (const float*)d_in[9];
  const float* b1    = (const float*)d_in[10];
  const float* w2    = (const float*)d_in[11];
  const float* b2    = (const float*)d_in[12];

  char* ws = (char*)d_ws;
  // Layout (byte offsets), with lifetime-based reuse:
  u16*   wT_qkv = (u16*)  (ws);              // [0, 6291456)        3072x1024 bf16; dead after qkv GEMM
  u16*   wT_out = (u16*)  (ws +  6291456);   // [6291456, 8388608)  dead after out-proj
  u16*   wT_w1  = (u16*)  (ws +  8388608);   // [8388608, 16777216) dead after MLP1
  u16*   wT_w2  = (u16*)  (ws + 16777216);   // [16777216, 25165824)
  u16*   h1     = (u16*)  (ws + 25165824);   // [25165824, 29360128) bf16; reused as o
  u16*   qkv    = (u16*)  (ws + 29360128);   // [29360128, 41943040) bf16; dead after attn_out
  float* Ssum   = (float*)(ws + 41943040);   // [41943040, 50331648) f32 (S^T per (h,c)); dead after attn_out
  float* ksum   = (float*)(ws + 50331648);   // 16*32*64 f32
  float* x2     = (float*)(ws + 50462720);   // [50462720, 58851328) f32
  u16*   h2     = (u16*)  (ws + 58851328);   // [58851328, 63045632) bf16
  u16*   o      = h1;
  u16*   a1     = qkv;                        // 2048x4096 bf16: [29360128, 46137344) over dead qkv+Ssum
  // out-proj split-4 partials (2048x1024 bf16 = 4194304 B each): dead qkv+Ssum region, BEFORE a1 is written
  u16*   Pa0    = (u16*)(ws + 29360128);      // [29360128, 46137344), stride 4194304 B
  size_t PaStride = 2097152;                  // elements
  // MLP2 split-4 partials: dead wT_qkv+wT_out+wT_w1 = [0, 16777216)
  u16*   Pm0    = (u16*)(ws);
  u16*   Pm1    = (u16*)(ws +  4194304);
  u16*   Pm2    = (u16*)(ws +  8388608);
  u16*   Pm3    = (u16*)(ws + 12582912);
  size_t PmStride = 2097152;                  // elements
  float* outp   = (float*)d_out;

  TD t0{qkv_w, wT_qkv, 1024, 3072,  96, 3072};
  TD t1{out_w, wT_out, 1024, 1024,  32, 1024};
  TD t2{w1,    wT_w1,  1024, 4096, 128, 4096};
  TD t3{w2,    wT_w2,  4096, 1024,  32, 4096};
  transpose4<<<12288, dim3(32,8), 0, stream>>>(t0, t1, t2, t3);

  ln_f32<<<2048, 256, 0, stream>>>(x, ln1_g, ln1_b, h1);
  gemm_bt<0><<<dim3(16, 24, 1), 512, 0, stream>>>(h1, wT_qkv, qkv_b, nullptr, qkv, 3072, 1024, 0);

  attn_chunksum<<<dim3(32, 16), 256, 0, stream>>>(qkv, Ssum, ksum);
  attn_prefix  <<<dim3(16, 16), 256, 0, stream>>>(Ssum, ksum);
  attn_out     <<<dim3(32, 16), 256, 0, stream>>>(qkv, Ssum, ksum, o);

  // out-proj: split-K x4 -> bf16 partials -> fused reduce(+out_b +x) + LN2 -> x2 (f32), h2 (bf16)
  gemm_bt<3><<<dim3(16, 8, 4), 512, 0, stream>>>(o, wT_out, nullptr, nullptr, Pa0, 1024, 1024, PaStride);
  ln2_fused<<<2048, 256, 0, stream>>>(Pa0, Pa0 + PaStride, Pa0 + 2*PaStride, Pa0 + 3*PaStride,
                                      out_b, x, ln2_g, ln2_b, x2, h2);

  gemm_bt<1><<<dim3(16, 32, 1), 512, 0, stream>>>(h2, wT_w1, b1, nullptr, a1, 4096, 1024, 0);

  // MLP2: split-K x4 -> partials -> reduce(+b2 +x2) -> d_out (f32)
  gemm_bt<3><<<dim3(16, 8, 4), 512, 0, stream>>>(a1, wT_w2, nullptr, nullptr, Pm0, 1024, 4096, PmStride);
  reduce4<<<2048, 256, 0, stream>>>(Pm0, Pm1, Pm2, Pm3, b2, x2, outp);
}

// Round 10
// 129.380 us; speedup vs baseline: 1.9871x; 1.1030x over previous
//
#include <hip/hip_runtime.h>

typedef unsigned short u16;
typedef __bf16 bf16x8 __attribute__((ext_vector_type(8)));
typedef float f32x4 __attribute__((ext_vector_type(4)));
typedef unsigned short u16x8 __attribute__((ext_vector_type(8)));
typedef unsigned short u16x4 __attribute__((ext_vector_type(4)));

__device__ __forceinline__ float bf2f(u16 u){
  union { unsigned i; float f; } v; v.i = ((unsigned)u) << 16; return v.f;
}
__device__ __forceinline__ u16 f2bf(float f){
  union { float f; unsigned i; } v; v.f = f;
  unsigned r = v.i + 0x7FFFu + ((v.i >> 16) & 1u);
  return (u16)(r >> 16);
}
// elu(x)+1:  x>0 -> x+1 ; x<=0 -> exp(x)
__device__ __forceinline__ float elup(float x){ return x > 0.f ? x + 1.f : expf(x); }

__device__ __forceinline__ void gload_lds16(const void* gsrc, void* ldst){
  __builtin_amdgcn_global_load_lds(
      (__attribute__((address_space(1))) void*)(unsigned long long)gsrc,
      (__attribute__((address_space(3))) void*)(unsigned)(unsigned long long)ldst,
      16, 0, 0);
}

// ---------------- prep: 4 weight transposes (f32->bf16) + LN1, one launch ----------------
struct TD { const float* in; u16* out; int R, Cc, cx, ntiles; };

__global__ __launch_bounds__(256) void prep(TD d0, TD d1, TD d2, TD d3,
                                            const float* __restrict__ x, const float* __restrict__ g,
                                            const float* __restrict__ b, u16* __restrict__ y){
  __shared__ u16 tile[32][33];
  __shared__ float ls[4], ls2[4];
  int bidx = blockIdx.x, tid = threadIdx.x;
  if (bidx >= 12288){
    // ---- LayerNorm row of 1024: f32 in, bf16 out ----
    int row = bidx - 12288;
    size_t base = (size_t)row*1024 + tid*4;
    f32x4 xv = *(const f32x4*)(x + base);
    float v0=xv[0], v1=xv[1], v2=xv[2], v3=xv[3];
    float s  = v0+v1+v2+v3;
    float s2 = v0*v0+v1*v1+v2*v2+v3*v3;
    #pragma unroll
    for (int off=32; off>0; off>>=1){ s += __shfl_xor(s, off); s2 += __shfl_xor(s2, off); }
    if ((tid & 63) == 0){ ls[tid>>6] = s; ls2[tid>>6] = s2; }
    __syncthreads();
    float ts = ls[0]+ls[1]+ls[2]+ls[3];
    float ts2 = ls2[0]+ls2[1]+ls2[2]+ls2[3];
    float mean = ts*(1.f/1024.f);
    float var  = ts2*(1.f/1024.f) - mean*mean;
    float rstd = rsqrtf(var + 1e-5f);
    f32x4 gv = *(const f32x4*)(g + tid*4);
    f32x4 bv = *(const f32x4*)(b + tid*4);
    u16x4 ov;
    ov[0]=f2bf((v0-mean)*rstd*gv[0]+bv[0]);
    ov[1]=f2bf((v1-mean)*rstd*gv[1]+bv[1]);
    ov[2]=f2bf((v2-mean)*rstd*gv[2]+bv[2]);
    ov[3]=f2bf((v3-mean)*rstd*gv[3]+bv[3]);
    *(u16x4*)(y + base) = ov;
    return;
  }
  // ---- transpose+cast ----
  int bb = bidx;
  TD d;
  if (bb < d0.ntiles) d = d0;
  else { bb -= d0.ntiles;
    if (bb < d1.ntiles) d = d1;
    else { bb -= d1.ntiles;
      if (bb < d2.ntiles) d = d2;
      else { bb -= d2.ntiles; d = d3; } } }
  int c0 = (bb % d.cx) * 32, r0 = (bb / d.cx) * 32;
  int tx = tid & 31, ty = tid >> 5; // 32 x 8
  #pragma unroll
  for (int i=0;i<4;i++)
    tile[ty + i*8][tx] = f2bf(d.in[(size_t)(r0 + ty + i*8)*d.Cc + c0 + tx]);
  __syncthreads();
  #pragma unroll
  for (int i=0;i<4;i++)
    d.out[(size_t)(c0 + ty + i*8)*d.R + r0 + tx] = tile[tx][ty + i*8];
}

// ---------------- fused split-K reduce(+bias+residual) -> x2 (f32) AND LayerNorm -> h2 (bf16) ----------------
__global__ __launch_bounds__(256) void ln2_fused(const u16* __restrict__ P0, const u16* __restrict__ P1,
                                                 const u16* __restrict__ P2, const u16* __restrict__ P3,
                                                 const float* __restrict__ bias, const float* __restrict__ xres,
                                                 const float* __restrict__ g, const float* __restrict__ b,
                                                 float* __restrict__ x2, u16* __restrict__ h2){
  int row = blockIdx.x, tid = threadIdx.x;
  size_t base = (size_t)row*1024 + tid*4;
  u16x4 a0 = *(const u16x4*)(P0 + base);
  u16x4 a1 = *(const u16x4*)(P1 + base);
  u16x4 a2 = *(const u16x4*)(P2 + base);
  u16x4 a3 = *(const u16x4*)(P3 + base);
  f32x4 rv = *(const f32x4*)(xres + base);
  f32x4 bv = *(const f32x4*)(bias + tid*4);
  f32x4 v;
  #pragma unroll
  for (int j=0;j<4;j++) v[j] = (bf2f(a0[j])+bf2f(a1[j])) + (bf2f(a2[j])+bf2f(a3[j])) + bv[j] + rv[j];
  *(f32x4*)(x2 + base) = v;
  float s  = v[0]+v[1]+v[2]+v[3];
  float s2 = v[0]*v[0]+v[1]*v[1]+v[2]*v[2]+v[3]*v[3];
  #pragma unroll
  for (int off=32; off>0; off>>=1){ s += __shfl_xor(s, off); s2 += __shfl_xor(s2, off); }
  __shared__ float ls[4], ls2[4];
  if ((tid & 63) == 0){ ls[tid>>6] = s; ls2[tid>>6] = s2; }
  __syncthreads();
  float ts = ls[0]+ls[1]+ls[2]+ls[3];
  float ts2 = ls2[0]+ls2[1]+ls2[2]+ls2[3];
  float mean = ts*(1.f/1024.f);
  float var  = ts2*(1.f/1024.f) - mean*mean;
  float rstd = rsqrtf(var + 1e-5f);
  f32x4 gv = *(const f32x4*)(g + tid*4);
  f32x4 bb = *(const f32x4*)(b + tid*4);
  u16x4 ov;
  #pragma unroll
  for (int j=0;j<4;j++) ov[j] = f2bf((v[j]-mean)*rstd*gv[j]+bb[j]);
  *(u16x4*)(h2 + base) = ov;
}

// ---------------- GEMM: C[M][N] = A[M][K] * BT[N][K]^T (+ bias) ----------------
// 128x128 tile, BK=64, 8 waves (512 thr), double-buffered LDS, T2 both-sides XOR swizzle:
//   LDS row = 128 B; logical LDS[r][byte p16] holds global chunk (p16>>4)^(r&7).
//   Staging: linear LDS dest (gload_lds), global source chunk = (lane&7)^(lane>>3) — per-lane const.
//   Read: byte offset ((kk*64 + (lane>>4)*16) ^ ((lrow&7)<<4)) within row.
// EPI 0: +bias -> bf16 out.  1: gelu(+bias) -> bf16 out.
// EPI 3: split-K bf16 PARTIAL (no bias); gridDim.z = #splits, partial z at out + z*pstride.
template<int EPI>
__global__ __launch_bounds__(512, 4) void gemm_bt(const u16* __restrict__ A, const u16* __restrict__ BT,
                                                  const float* __restrict__ bias, const float* __restrict__ res,
                                                  void* __restrict__ out, int N, int K, size_t pstride){
  __shared__ u16 As[2][128*64];
  __shared__ u16 Bs[2][128*64];
  int tid = threadIdx.x;
  int w = tid >> 6, lane = tid & 63;
  int m0 = blockIdx.x * 128, n0 = blockIdx.y * 128;
  int Kc = K / gridDim.z;
  int kbase = blockIdx.z * Kc;
  int nt = Kc / 64;

  f32x4 acc[2][4] = {};

  int l3 = lane >> 3, l7 = lane & 7;
  // pre-swizzled global source: chunk (l7^l3), row w*16 + l3 (+8 for second issue)
  const u16* aSrc = A  + (size_t)(m0 + w*16 + l3)*K + kbase + (l7 ^ l3)*8;
  const u16* bSrc = BT + (size_t)(n0 + w*16 + l3)*K + kbase + (l7 ^ l3)*8;
  int r0 = (w>>1)*32, c0 = (w&1)*64;
  int lrow = lane & 15, g4 = lane >> 4;
  int swz = (lrow & 7) << 4;

  // prologue: stage tile 0 into buffer 0 (wave w covers rows w*16..w*16+15 of both A,B)
  {
    u16* aD = As[0] + w*16*64;
    u16* bD = Bs[0] + w*16*64;
    gload_lds16(aSrc,                aD);
    gload_lds16(aSrc + (size_t)8*K,  aD + 8*64);
    gload_lds16(bSrc,                bD);
    gload_lds16(bSrc + (size_t)8*K,  bD + 8*64);
  }
  __syncthreads();

  int cur = 0;
  for (int t = 0; t < nt; ++t){
    if (t + 1 < nt){
      int k0 = (t+1)*64;
      u16* aD = As[cur^1] + w*16*64;
      u16* bD = Bs[cur^1] + w*16*64;
      gload_lds16(aSrc + k0,               aD);
      gload_lds16(aSrc + (size_t)8*K + k0, aD + 8*64);
      gload_lds16(bSrc + k0,               bD);
      gload_lds16(bSrc + (size_t)8*K + k0, bD + 8*64);
    }
    const char* Ab = (const char*)As[cur];
    const char* Bb = (const char*)Bs[cur];
    #pragma unroll
    for (int kk=0; kk<2; kk++){
      int ko = (kk*64 + g4*16) ^ swz;   // swizzled byte offset within 128B row
      bf16x8 af[2], bfv[4];
      #pragma unroll
      for (int mi=0;mi<2;mi++) af[mi]  = *(const bf16x8*)(Ab + (r0 + mi*16 + lrow)*128 + ko);
      #pragma unroll
      for (int ni=0;ni<4;ni++) bfv[ni] = *(const bf16x8*)(Bb + (c0 + ni*16 + lrow)*128 + ko);
      #pragma unroll
      for (int mi=0;mi<2;mi++)
        #pragma unroll
        for (int ni=0;ni<4;ni++)
          acc[mi][ni] = __builtin_amdgcn_mfma_f32_16x16x32_bf16(af[mi], bfv[ni], acc[mi][ni], 0, 0, 0);
    }
    __syncthreads();
    cur ^= 1;
  }

  int lgr = lane >> 4;
  u16* pout = (EPI == 3) ? ((u16*)out + (size_t)blockIdx.z * pstride) : (u16*)out;
  #pragma unroll
  for (int mi=0;mi<2;mi++){
    #pragma unroll
    for (int j=0;j<4;j++){
      int row = m0 + r0 + mi*16 + lgr*4 + j;
      #pragma unroll
      for (int ni=0;ni<4;ni++){
        int col = n0 + c0 + ni*16 + lrow;
        size_t idx = (size_t)row*N + col;
        if constexpr (EPI == 3){
          pout[idx] = f2bf(acc[mi][ni][j]);
        } else {
          float v = acc[mi][ni][j] + bias[col];
          if constexpr (EPI == 0){
            ((u16*)out)[idx] = f2bf(v);
          } else {
            v = 0.5f * v * (1.f + erff(v * 0.70710678118654752f));
            ((u16*)out)[idx] = f2bf(v);
          }
        }
      }
    }
  }
}

// ---------------- split-K reduction: out = sum(4 partials) + bias + res (f32 out) ----------------
__global__ __launch_bounds__(256) void reduce4(const u16* __restrict__ P0, const u16* __restrict__ P1,
                                               const u16* __restrict__ P2, const u16* __restrict__ P3,
                                               const float* __restrict__ bias, const float* __restrict__ res,
                                               float* __restrict__ out){
  size_t i = ((size_t)blockIdx.x*256 + threadIdx.x)*4;
  u16x4 a = *(const u16x4*)(P0 + i);
  u16x4 b = *(const u16x4*)(P1 + i);
  u16x4 c = *(const u16x4*)(P2 + i);
  u16x4 d = *(const u16x4*)(P3 + i);
  f32x4 rv = *(const f32x4*)(res + i);
  f32x4 bv = *(const f32x4*)(bias + (i & 1023));
  f32x4 o;
  #pragma unroll
  for (int j=0;j<4;j++) o[j] = (bf2f(a[j]) + bf2f(b[j])) + (bf2f(c[j]) + bf2f(d[j])) + bv[j] + rv[j];
  *(f32x4*)(out + i) = o;
}

// ---------------- attention: per-(head,chunk) S^T[e][d] = sum_t V[t][e]*K'[t][d], Ks[d]=sum_t K'[t][d] ----------------
__global__ __launch_bounds__(256) void attn_chunksum(const u16* __restrict__ qkv, float* __restrict__ S,
                                                     float* __restrict__ Ks){
  __shared__ u16 KT[64*72];  // [d][t] bf16, elup'd
  __shared__ u16 VT[64*72];  // [e][t] bf16 (raw)
  int c = blockIdx.x, h = blockIdx.y, tid = threadIdx.x;
  int t = tid >> 2, seg = tid & 3, e0 = seg*16;
  size_t rowb = (size_t)(c*64 + t)*3072 + h*64 + e0;
  u16x8 k0 = *(const u16x8*)(qkv + rowb + 1024);
  u16x8 k1 = *(const u16x8*)(qkv + rowb + 1032);
  u16x8 v0 = *(const u16x8*)(qkv + rowb + 2048);
  u16x8 v1 = *(const u16x8*)(qkv + rowb + 2056);
  #pragma unroll
  for (int i=0;i<8;i++){
    KT[(e0 + i)*72 + t]     = f2bf(elup(bf2f(k0[i])));
    KT[(e0 + 8 + i)*72 + t] = f2bf(elup(bf2f(k1[i])));
    VT[(e0 + i)*72 + t]     = v0[i];
    VT[(e0 + 8 + i)*72 + t] = v1[i];
  }
  __syncthreads();

  int w = tid >> 6, lane = tid & 63;
  int lr = lane & 15, lk = (lane>>4)*8, g = lane >> 4, cl = lane & 15;
  bf16x8 av_[2];
  #pragma unroll
  for (int kk=0;kk<2;kk++) av_[kk] = *(const bf16x8*)(VT + (w*16 + lr)*72 + kk*32 + lk);
  f32x4 acc[4] = {};
  #pragma unroll
  for (int di=0;di<4;di++){
    #pragma unroll
    for (int kk=0;kk<2;kk++){
      bf16x8 bk = *(const bf16x8*)(KT + (di*16 + lr)*72 + kk*32 + lk);
      acc[di] = __builtin_amdgcn_mfma_f32_16x16x32_bf16(av_[kk], bk, acc[di], 0, 0, 0);
    }
  }
  size_t base = (size_t)(h*32 + c)*4096;
  #pragma unroll
  for (int di=0;di<4;di++)
    #pragma unroll
    for (int j=0;j<4;j++)
      S[base + (size_t)(w*16 + g*4 + j)*64 + di*16 + cl] = acc[di][j];

  float s = 0.f;
  #pragma unroll
  for (int i=0;i<16;i++) s += bf2f(KT[t*72 + e0 + i]);
  s += __shfl_xor(s, 1); s += __shfl_xor(s, 2);
  if (seg == 0) Ks[(size_t)(h*32 + c)*64 + t] = s;
}

// ---------------- attention: exclusive prefix over chunks (per head, element-parallel) ----------------
__global__ __launch_bounds__(256) void attn_prefix(float* __restrict__ S, float* __restrict__ Ks){
  int g = blockIdx.x, h = blockIdx.y, tid = threadIdx.x;
  size_t hb = (size_t)h * 32 * 4096;
  int idx = g*256 + tid;
  float run = 0.f;
  for (int c=0; c<32; c++){
    size_t p = hb + (size_t)c*4096 + idx;
    float v = S[p]; S[p] = run; run += v;
  }
  if (g == 0 && tid < 64){
    float r2 = 0.f;
    for (int c=0; c<32; c++){
      size_t p = (size_t)(h*32 + c)*64 + tid;
      float v = Ks[p]; Ks[p] = r2; r2 += v;
    }
  }
}

// ---------------- attention: O = Q*S_prev^T + tril(QK^T)V, den = Q*kp + rowsum(A); MFMA ----------------
__global__ __launch_bounds__(256) void attn_out(const u16* __restrict__ qkv, const float* __restrict__ S,
                                                const float* __restrict__ Ks, u16* __restrict__ o){
  __shared__ u16 Qs [64*72];
  __shared__ u16 Ksh[64*72];
  __shared__ u16 VT [64*72];
  __shared__ u16 SpT[64*72];
  __shared__ u16 Am [64*72];
  __shared__ float kp[64], den[64];
  int c = blockIdx.x, h = blockIdx.y, tid = threadIdx.x;
  int t = tid >> 2, seg = tid & 3, e0 = seg*16;

  size_t rowb = (size_t)(c*64 + t)*3072 + h*64 + e0;
  u16x8 q0 = *(const u16x8*)(qkv + rowb);
  u16x8 q1 = *(const u16x8*)(qkv + rowb + 8);
  u16x8 k0 = *(const u16x8*)(qkv + rowb + 1024);
  u16x8 k1 = *(const u16x8*)(qkv + rowb + 1032);
  u16x8 v0 = *(const u16x8*)(qkv + rowb + 2048);
  u16x8 v1 = *(const u16x8*)(qkv + rowb + 2056);
  #pragma unroll
  for (int i=0;i<8;i++){
    Qs [t*72 + e0 + i]     = f2bf(elup(bf2f(q0[i])));
    Qs [t*72 + e0 + 8 + i] = f2bf(elup(bf2f(q1[i])));
    Ksh[t*72 + e0 + i]     = f2bf(elup(bf2f(k0[i])));
    Ksh[t*72 + e0 + 8 + i] = f2bf(elup(bf2f(k1[i])));
    VT [(e0 + i)*72 + t]     = v0[i];
    VT [(e0 + 8 + i)*72 + t] = v1[i];
  }
  size_t sbase = (size_t)(h*32 + c)*4096;
  {
    const f32x4* sp = (const f32x4*)(S + sbase + (size_t)t*64 + e0);
    #pragma unroll
    for (int qd=0;qd<4;qd++){
      f32x4 v = sp[qd];
      #pragma unroll
      for (int j=0;j<4;j++) SpT[t*72 + e0 + qd*4 + j] = f2bf(v[j]);
    }
  }
  if (tid < 64) kp[tid] = Ks[(size_t)(h*32 + c)*64 + tid];
  __syncthreads();

  int w = tid >> 6, lane = tid & 63;
  int lr = lane & 15, lk = (lane>>4)*8, g = lane >> 4, cl = lane & 15;

  bf16x8 aq[2];
  #pragma unroll
  for (int kk=0;kk<2;kk++) aq[kk] = *(const bf16x8*)(Qs + (w*16 + lr)*72 + kk*32 + lk);

  f32x4 acc[4] = {};
  #pragma unroll
  for (int ni=0;ni<4;ni++){
    #pragma unroll
    for (int kk=0;kk<2;kk++){
      bf16x8 bs = *(const bf16x8*)(SpT + (ni*16 + lr)*72 + kk*32 + lk);
      acc[ni] = __builtin_amdgcn_mfma_f32_16x16x32_bf16(aq[kk], bs, acc[ni], 0, 0, 0);
    }
  }
  #pragma unroll
  for (int si=0;si<4;si++){
    f32x4 qk = {};
    #pragma unroll
    for (int kk=0;kk<2;kk++){
      bf16x8 bk = *(const bf16x8*)(Ksh + (si*16 + lr)*72 + kk*32 + lk);
      qk = __builtin_amdgcn_mfma_f32_16x16x32_bf16(aq[kk], bk, qk, 0, 0, 0);
    }
    #pragma unroll
    for (int j=0;j<4;j++){
      int rowt = w*16 + g*4 + j;
      int scol = si*16 + cl;
      Am[rowt*72 + scol] = f2bf((scol <= rowt) ? qk[j] : 0.f);
    }
  }
  __syncthreads();

  {
    float dsum = 0.f;
    #pragma unroll
    for (int i=0;i<16;i++) dsum += bf2f(Am[t*72 + e0 + i]);
    #pragma unroll
    for (int i=0;i<16;i++) dsum += bf2f(Qs[t*72 + e0 + i]) * kp[e0 + i];
    dsum += __shfl_xor(dsum, 1); dsum += __shfl_xor(dsum, 2);
    if (seg == 0) den[t] = dsum;
  }
  {
    bf16x8 aa[2];
    #pragma unroll
    for (int kk=0;kk<2;kk++) aa[kk] = *(const bf16x8*)(Am + (w*16 + lr)*72 + kk*32 + lk);
    #pragma unroll
    for (int ni=0;ni<4;ni++){
      #pragma unroll
      for (int kk=0;kk<2;kk++){
        bf16x8 bv = *(const bf16x8*)(VT + (ni*16 + lr)*72 + kk*32 + lk);
        acc[ni] = __builtin_amdgcn_mfma_f32_16x16x32_bf16(aa[kk], bv, acc[ni], 0, 0, 0);
      }
    }
  }
  __syncthreads();

  #pragma unroll
  for (int j=0;j<4;j++){
    int rowt = w*16 + g*4 + j;
    float inv = 1.f/(den[rowt] + 1e-6f);
    #pragma unroll
    for (int ni=0;ni<4;ni++)
      o[(size_t)(c*64 + rowt)*1024 + h*64 + ni*16 + cl] = f2bf(acc[ni][j]*inv);
  }
}

// ---------------- launch ----------------
extern "C" void kernel_launch(void* const* d_in, const int* in_sizes, int n_in,
                              void* d_out, int out_size, void* d_ws, size_t ws_size,
                              hipStream_t stream) {
  (void)in_sizes; (void)n_in; (void)out_size; (void)ws_size;
  const float* x     = (const float*)d_in[0];
  const float* qkv_w = (const float*)d_in[1];
  const float* qkv_b = (const float*)d_in[2];
  const float* out_w = (const float*)d_in[3];
  const float* out_b = (const float*)d_in[4];
  const float* ln1_g = (const float*)d_in[5];
  const float* ln1_b = (const float*)d_in[6];
  const float* ln2_g = (const float*)d_in[7];
  const float* ln2_b = (const float*)d_in[8];
  const float* w1    = (const float*)d_in[9];
  const float* b1    = (const float*)d_in[10];
  const float* w2    = (const float*)d_in[11];
  const float* b2    = (const float*)d_in[12];

  char* ws = (char*)d_ws;
  // Layout (byte offsets), with lifetime-based reuse:
  u16*   wT_qkv = (u16*)  (ws);              // [0, 6291456)        3072x1024 bf16; dead after qkv GEMM
  u16*   wT_out = (u16*)  (ws +  6291456);   // [6291456, 8388608)  dead after out-proj
  u16*   wT_w1  = (u16*)  (ws +  8388608);   // [8388608, 16777216) dead after MLP1
  u16*   wT_w2  = (u16*)  (ws + 16777216);   // [16777216, 25165824)
  u16*   h1     = (u16*)  (ws + 25165824);   // [25165824, 29360128) bf16; reused as o
  u16*   qkv    = (u16*)  (ws + 29360128);   // [29360128, 41943040) bf16; dead after attn_out
  float* Ssum   = (float*)(ws + 41943040);   // [41943040, 50331648) f32 (S^T per (h,c)); dead after attn_out
  float* ksum   = (float*)(ws + 50331648);   // 16*32*64 f32
  float* x2     = (float*)(ws + 50462720);   // [50462720, 58851328) f32
  u16*   h2     = (u16*)  (ws + 58851328);   // [58851328, 63045632) bf16
  u16*   o      = h1;
  u16*   a1     = qkv;                        // 2048x4096 bf16: [29360128, 46137344) over dead qkv+Ssum
  // out-proj split-4 partials (2048x1024 bf16 = 4194304 B each): dead qkv+Ssum region, BEFORE a1 is written
  u16*   Pa0    = (u16*)(ws + 29360128);      // [29360128, 46137344), stride 4194304 B
  size_t PaStride = 2097152;                  // elements
  // MLP2 split-4 partials: dead wT_qkv+wT_out+wT_w1 = [0, 16777216)
  u16*   Pm0    = (u16*)(ws);
  u16*   Pm1    = (u16*)(ws +  4194304);
  u16*   Pm2    = (u16*)(ws +  8388608);
  u16*   Pm3    = (u16*)(ws + 12582912);
  size_t PmStride = 2097152;                  // elements
  float* outp   = (float*)d_out;

  TD t0{qkv_w, wT_qkv, 1024, 3072,  96, 3072};
  TD t1{out_w, wT_out, 1024, 1024,  32, 1024};
  TD t2{w1,    wT_w1,  1024, 4096, 128, 4096};
  TD t3{w2,    wT_w2,  4096, 1024,  32, 4096};
  // prep: 12288 transpose tiles + 2048 LN1 rows in one launch
  prep<<<14336, 256, 0, stream>>>(t0, t1, t2, t3, x, ln1_g, ln1_b, h1);

  gemm_bt<0><<<dim3(16, 24, 1), 512, 0, stream>>>(h1, wT_qkv, qkv_b, nullptr, qkv, 3072, 1024, 0);

  attn_chunksum<<<dim3(32, 16), 256, 0, stream>>>(qkv, Ssum, ksum);
  attn_prefix  <<<dim3(16, 16), 256, 0, stream>>>(Ssum, ksum);
  attn_out     <<<dim3(32, 16), 256, 0, stream>>>(qkv, Ssum, ksum, o);

  // out-proj: split-K x4 -> bf16 partials -> fused reduce(+out_b +x) + LN2 -> x2 (f32), h2 (bf16)
  gemm_bt<3><<<dim3(16, 8, 4), 512, 0, stream>>>(o, wT_out, nullptr, nullptr, Pa0, 1024, 1024, PaStride);
  ln2_fused<<<2048, 256, 0, stream>>>(Pa0, Pa0 + PaStride, Pa0 + 2*PaStride, Pa0 + 3*PaStride,
                                      out_b, x, ln2_g, ln2_b, x2, h2);

  gemm_bt<1><<<dim3(16, 32, 1), 512, 0, stream>>>(h2, wT_w1, b1, nullptr, a1, 4096, 1024, 0);

  // MLP2: split-K x4 -> partials -> reduce(+b2 +x2) -> d_out (f32)
  gemm_bt<3><<<dim3(16, 8, 4), 512, 0, stream>>>(a1, wT_w2, nullptr, nullptr, Pm0, 1024, 4096, PmStride);
  reduce4<<<2048, 256, 0, stream>>>(Pm0, Pm1, Pm2, Pm3, b2, x2, outp);
}